// Round 14
// baseline (1093.426 us; speedup 1.0000x reference)
//
#include <hip/hip_runtime.h>
#include <hip/hip_bf16.h>
#include <math.h>

typedef __attribute__((ext_vector_type(8))) short short8;
typedef __attribute__((ext_vector_type(4))) float f32x4;
typedef unsigned short u16;
typedef unsigned int u32;

#define CL 16              // chunk length (timesteps per handoff)
#define NCHUNK 24          // 384 / CL
#define RING 4             // ring depth per (layer,stream)
#define CHSZ (16*CL*128)   // u16 per chunk slot = 32768

__device__ __forceinline__ u16 f2bf(float f){
  u32 x = __float_as_uint(f);
  u32 r = x + 0x7fffu + ((x >> 16) & 1u);
  return (u16)(r >> 16);
}
__device__ __forceinline__ float bf2f(u16 u){
  return __uint_as_float(((u32)u) << 16);
}
__device__ __forceinline__ f32x4 mfma16(short8 a, short8 b, f32x4 c){
  return __builtin_amdgcn_mfma_f32_16x16x32_bf16(a, b, c, 0, 0, 0);
}

// ---------------- init: zero FF accumulator / ssq / sync flags / Mx ----------------
__global__ void k_init(float* S, float* ssq, u32* Flg, float* Mx){
  int i = blockIdx.x*256 + threadIdx.x;
  if (i < 32768){ S[i] = 0.f; return; }
  i -= 32768;
  if (i < 16){ ssq[i] = 0.f; return; }
  i -= 16;
  if (i < 4096){ Flg[i] = 0u; return; }
  i -= 4096;
  if (i < 4096){ Mx[i] = 0.f; return; }
}

// ---------------- weight prep: conv weights [k][f][c] bf16, W1 transposed ----------------
__global__ void k_wprep(const float* __restrict__ wr, const float* __restrict__ wi,
                        const float* __restrict__ w1,
                        u16* WtR, u16* WtI, u16* WtIN, u16* W1t){
  int i = blockIdx.x*256 + threadIdx.x;
  if (i < 131072){
    int k = i >> 12, r = i & 4095, f = r >> 6, c = r & 63;
    float a = wr[(k<<12) + (c<<6) + f];
    float b = wi[(k<<12) + (c<<6) + f];
    WtR[i] = f2bf(a); WtI[i] = f2bf(b); WtIN[i] = f2bf(-b);
  } else if (i < 262144){
    int j = i - 131072;           // j = col*128 + k ;  W1t[col][k] = w1[k][col]
    int col = j >> 7, k = j & 127;
    W1t[j] = f2bf(w1[(k<<10) + col]);
  }
}

// ---------------- GRU weight prep (LDS-tiled transpose, coalesced both sides) ----------------
__global__ __launch_bounds__(256) void k_wprep2(
    const float* __restrict__ g0_kr, const float* __restrict__ g0_ki,
    const float* __restrict__ gs_kr, const float* __restrict__ gs_ki,
    const float* __restrict__ g0_rkr, const float* __restrict__ g0_rki,
    const float* __restrict__ gs_rkr, const float* __restrict__ gs_rki,
    u16* __restrict__ KT, u16* __restrict__ RKT){
  __shared__ float tile[128][33];
  int bid = blockIdx.x;
  int ct = bid % 12; int lm = (bid/12) & 31; int which = bid / (12*32);
  int m = lm & 1, l = lm >> 1;
  int c0 = ct*32;
  int tid = threadIdx.x;
  for (int idx = tid; idx < 128*32; idx += 256){
    int k = idx >> 5, cc = idx & 31;
    float v;
    if (!which){
      if (l == 0) v = (k < 64) ? (m ? g0_ki : g0_kr)[k*384 + c0+cc] : 0.f;
      else        v = (m ? gs_ki : gs_kr)[((size_t)(l-1)*128 + k)*384 + c0+cc];
    } else {
      if (l == 0) v = (m ? g0_rki : g0_rkr)[k*384 + c0+cc];
      else        v = (m ? gs_rki : gs_rkr)[((size_t)(l-1)*128 + k)*384 + c0+cc];
    }
    tile[k][cc] = v;
  }
  __syncthreads();
  u16* dst = (which ? RKT : KT) + (size_t)lm*384*128;
  for (int idx = tid; idx < 32*128; idx += 256){
    int cc = idx >> 7, k = idx & 127;
    dst[(size_t)(c0+cc)*128 + k] = f2bf(tile[k][cc]);
  }
}

// ---------------- conv1d (K=32, SAME padlow=15) + BN -> X0 bf16 [2][16][384][64] ----------------
// 32-wide t-tiles: two 16x16 output tiles share one staged window and one weight
// fetch (each weight fragment feeds 8 MFMAs). grid = 16 batches x 12 tiles.
__global__ __launch_bounds__(256) void k_conv(
    const float* __restrict__ hr, const float* __restrict__ hi,
    const u16* __restrict__ WtR, const u16* __restrict__ WtI, const u16* __restrict__ WtIN,
    const float* __restrict__ gr, const float* __restrict__ gi,
    const float* __restrict__ vr, const float* __restrict__ vi,
    const float* __restrict__ br, const float* __restrict__ bi,
    const float* __restrict__ mr, const float* __restrict__ mi,
    u16* __restrict__ X0){
  __shared__ u16 xst[2*64*64];      // [part][row 0..62][c]; row = t - t0 + 15
  int tid = threadIdx.x;
  int bid = blockIdx.x;
  int b = bid / 12, t0 = (bid % 12) * 32;
  for (int el = tid; el < 2*63*64; el += 256){
    int part = el / (63*64); int rem = el % (63*64); int row = rem >> 6; int c = rem & 63;
    int tg = t0 + row - 15;
    const float* src = part ? hi : hr;
    float v = (tg >= 0 && tg < 384) ? src[((size_t)b*384 + tg)*64 + c] : 0.f;
    int idx = (part*64 + row)*64 + c;
    int byte = (idx<<1) ^ ((row&7)<<4);
    *(u16*)((char*)xst + byte) = f2bf(v);
  }
  __syncthreads();
  int lane = tid & 63, wid = tid >> 6, lr = lane & 15, lg = lane >> 4;
  f32x4 accr = {0,0,0,0}, acci = {0,0,0,0};
  f32x4 accr2 = {0,0,0,0}, acci2 = {0,0,0,0};
  for (int k = 0; k < 32; ++k){
    int row = lr + k;           // tile A rows [0,47)
    int row2 = row + 16;        // tile B rows [16,63)
    int swz = (row&7)<<4, swz2 = (row2&7)<<4;
    for (int ch = 0; ch < 2; ++ch){
      int c0 = ch*32 + lg*8;
      int idxr  = (0*64 + row )*64 + c0;
      int idxi  = (1*64 + row )*64 + c0;
      int idxr2 = (0*64 + row2)*64 + c0;
      int idxi2 = (1*64 + row2)*64 + c0;
      short8 ar  = *(const short8*)((const char*)xst + ((idxr <<1) ^ swz));
      short8 ai  = *(const short8*)((const char*)xst + ((idxi <<1) ^ swz));
      short8 ar2 = *(const short8*)((const char*)xst + ((idxr2<<1) ^ swz2));
      short8 ai2 = *(const short8*)((const char*)xst + ((idxi2<<1) ^ swz2));
      size_t wb = ((size_t)(k*64 + wid*16 + lr))*64 + c0;
      short8 bwr = *(const short8*)(WtR + wb);
      short8 bwi = *(const short8*)(WtI + wb);
      short8 bwn = *(const short8*)(WtIN + wb);
      accr  = mfma16(ar,  bwr, accr);
      accr  = mfma16(ai,  bwn, accr);
      acci  = mfma16(ai,  bwr, acci);
      acci  = mfma16(ar,  bwi, acci);
      accr2 = mfma16(ar2, bwr, accr2);
      accr2 = mfma16(ai2, bwn, accr2);
      acci2 = mfma16(ai2, bwr, acci2);
      acci2 = mfma16(ar2, bwi, acci2);
    }
  }
  int f = wid*16 + lr;
  float sr_ = gr[f] * rsqrtf(vr[f] + 1e-3f), or_ = br[f] - mr[f]*sr_;
  float si_ = gi[f] * rsqrtf(vi[f] + 1e-3f), oi_ = bi[f] - mi[f]*si_;
  for (int r = 0; r < 4; ++r){
    int t  = t0 + lg*4 + r;
    int t2 = t0 + 16 + lg*4 + r;
    X0[(((size_t)0*16 + b)*384 + t )*64 + f] = f2bf(accr[r] *sr_ + or_);
    X0[(((size_t)1*16 + b)*384 + t )*64 + f] = f2bf(acci[r] *si_ + oi_);
    X0[(((size_t)0*16 + b)*384 + t2)*64 + f] = f2bf(accr2[r]*sr_ + or_);
    X0[(((size_t)1*16 + b)*384 + t2)*64 + f] = f2bf(acci2[r]*si_ + oi_);
  }
}

// ---------------- persistent dataflow GRU scan (R7 protocol + MLP-batched staging) ----------------
// ONE launch, 64 resident blocks: block = (l = bid>>2, stream s = bid&3), 512 thr.
// Producer (l-1,sA/sB) -> consumer (l,s) per CL=16-step chunk through RING=4
// ring in HC, agent-scope atomic flags + release/acquire fences (load-bearing:
// R8/R10/R11/R12 variants all failed or regressed).
// NEW vs R13: staging issues ALL 16 global loads back-to-back into registers,
// THEN combines + LDS-writes (compiler barrier between). Raises per-thread
// outstanding loads ~4 -> 16; the post-invalidate cold-read phase (~11us of the
// 18.7us edge cost) is MSHR/MLP-limited, so this attacks it directly without
// touching the protocol. x-projection hoist retained.
__global__ __launch_bounds__(512,1) void k_scanp(
    const u16* __restrict__ X0, const u16* __restrict__ KT, const u16* __restrict__ RKT,
    const float* __restrict__ g0_br, const float* __restrict__ g0_bi,
    const float* __restrict__ gs_br, const float* __restrict__ gs_bi,
    u16* __restrict__ HC, u16* __restrict__ HS15, u32* Flg)
{
  int bid = blockIdx.x;
  int l = bid >> 2, s = bid & 3;

  __shared__ u16 xs[16*CL*128];     // 64KB staged x chunk (swizzled)
  __shared__ u16 hs2[2*16*128];     // 8KB double-buffered h (bf16, swizzled)
  __shared__ float bsh[4][128];     // folded biases: z(b0+b1), r(b0+b1), hx(b0), hr(b1)

  int tid = threadIdx.x, lane = tid & 63, wv = tid >> 6, lr = lane & 15, lg = lane >> 4;
  int m = s >> 1;

  // --- bias fold ---
  const float* Bsrc = (l == 0) ? (m ? g0_bi : g0_br)
                               : ((m ? gs_bi : gs_br) + (size_t)(l-1)*768);
  if (tid < 128){
    int j = tid;
    bsh[0][j] = Bsrc[j]       + Bsrc[384 + j];
    bsh[1][j] = Bsrc[128 + j] + Bsrc[384 + 128 + j];
    bsh[2][j] = Bsrc[256 + j];
    bsh[3][j] = Bsrc[384 + 256 + j];
  }
  // zero h LDS (both parities); bf16 0x0000 == 0.0
  for (int i = tid; i < 2048; i += 512) ((u32*)hs2)[i] = 0u;

  // --- weight fragments into registers (24 short8 per thread, once) ---
  const u16* Kp  = KT  + (size_t)(l*2 + m)*384*128;
  const u16* RKp = RKT + (size_t)(l*2 + m)*384*128;
  int cz = wv*16 + lr;
  short8 wz[8], wr2[8], whx[4], whr[4];
  #pragma unroll
  for (int ks = 0; ks < 4; ++ks){
    wz[ks]    = *(const short8*)(RKp + (size_t)cz*128 + ks*32 + lg*8);
    wz[4+ks]  = *(const short8*)(Kp  + (size_t)cz*128 + ks*32 + lg*8);
    wr2[ks]   = *(const short8*)(RKp + (size_t)(128+cz)*128 + ks*32 + lg*8);
    wr2[4+ks] = *(const short8*)(Kp  + (size_t)(128+cz)*128 + ks*32 + lg*8);
    whx[ks]   = *(const short8*)(Kp  + (size_t)(256+cz)*128 + ks*32 + lg*8);
    whr[ks]   = *(const short8*)(RKp + (size_t)(256+cz)*128 + ks*32 + lg*8);
  }

  float hreg[4] = {0.f, 0.f, 0.f, 0.f};

  __syncthreads();
  float bz, br_, bhx, bhr;
  {
    int j = wv*16 + lr;
    bz = bsh[0][j]; br_ = bsh[1][j]; bhx = bsh[2][j]; bhr = bsh[3][j];
  }

  u32* prodF = Flg;              // prod[i] at Flg[i*32]   (128B padded)
  u32* consF = Flg + 2048;       // cons[i] at Flg[2048+i*32]
  int sA = (s & 1) ? 1 : 0, sB = (s & 1) ? 2 : 3;
  int pA = (l-1)*4 + sA, pB = (l-1)*4 + sB;   // only used when l>0
  float sgn = (s & 1) ? 1.f : -1.f;
  int p = s & 1;                 // X0 part for l==0
  int me = l*4 + s;

  for (int c = 0; c < NCHUNK; ++c){
    int t0 = c * CL;
    int slot = c & (RING-1);

    // ---- waits (tid0 spins; others park at the barrier) ----
    if (tid == 0){
      int guard = 0;
      if (l > 0){
        while (__hip_atomic_load(&prodF[pA*32], __ATOMIC_RELAXED, __HIP_MEMORY_SCOPE_AGENT) < (u32)(c+1) ||
               __hip_atomic_load(&prodF[pB*32], __ATOMIC_RELAXED, __HIP_MEMORY_SCOPE_AGENT) < (u32)(c+1)){
          __builtin_amdgcn_s_sleep(1);
          if (++guard > 10000000) break;   // hang-avoid bailout
        }
      }
      if (l < 15 && c >= RING){           // ring backpressure: both consumers done with c-RING
        guard = 0;
        while (__hip_atomic_load(&consF[me*32], __ATOMIC_RELAXED, __HIP_MEMORY_SCOPE_AGENT) < (u32)(2*(c-RING+1))){
          __builtin_amdgcn_s_sleep(1);
          if (++guard > 10000000) break;
        }
      }
    }
    __syncthreads();

    // ---- stage x chunk into LDS (element = b(4b)|ttv(4b)|k8(4b), b = g>>8) ----
    // Loads-first / combine-second: maximizes outstanding loads per thread.
    if (l == 0){
      short8 v[8];
      #pragma unroll
      for (int it = 0; it < 8; ++it){
        int g = tid + it*512;
        int k8 = g & 15, ttv = (g>>4) & 15, b = g >> 8;
        short8 t = {0,0,0,0,0,0,0,0};
        if (k8 < 8) t = *(const short8*)(X0 + (((size_t)p*16 + b)*384 + t0 + ttv)*64 + k8*8);
        v[it] = t;
      }
      asm volatile("" ::: "memory");      // loads issued before any LDS write
      #pragma unroll
      for (int it = 0; it < 8; ++it){
        int g = tid + it*512;
        int k8 = g & 15, ttv = (g>>4) & 15, b = g >> 8;
        int byte = (((b*CL + ttv)*128 + k8*8) << 1) ^ ((b&7)<<4);
        *(short8*)((char*)xs + byte) = v[it];
      }
      __syncthreads();
    } else {
      // make producers' chunk data visible (cross-XCD: buffer_inv)
      __builtin_amdgcn_fence(__ATOMIC_ACQUIRE, "agent");
      const u16* baseA = HC + ((size_t)pA*RING + slot)*CHSZ;
      const u16* baseB = HC + ((size_t)pB*RING + slot)*CHSZ;
      short8 va[8], vb[8];
      #pragma unroll
      for (int it = 0; it < 8; ++it){
        int g = tid + it*512;
        int k8 = g & 15, ttv = (g>>4) & 15, b = g >> 8;
        size_t si = ((size_t)b*CL + ttv)*128 + k8*8;
        va[it] = *(const short8*)(baseA + si);
        vb[it] = *(const short8*)(baseB + si);
      }
      asm volatile("" ::: "memory");      // all 16 loads issued before combines
      #pragma unroll
      for (int it = 0; it < 8; ++it){
        int g = tid + it*512;
        int k8 = g & 15, ttv = (g>>4) & 15, b = g >> 8;
        short8 o;
        #pragma unroll
        for (int e = 0; e < 8; ++e){
          float f = bf2f((u16)va[it][e]) + sgn*bf2f((u16)vb[it][e]);
          o[e] = (short)f2bf(f);
        }
        int byte = (((b*CL + ttv)*128 + k8*8) << 1) ^ ((b&7)<<4);
        *(short8*)((char*)xs + byte) = o;
      }
      __syncthreads();                    // all staging reads complete before signaling
      if (tid == 0){
        __hip_atomic_fetch_add(&consF[pA*32], 1u, __ATOMIC_RELAXED, __HIP_MEMORY_SCOPE_AGENT);
        __hip_atomic_fetch_add(&consF[pB*32], 1u, __ATOMIC_RELAXED, __HIP_MEMORY_SCOPE_AGENT);
      }
    }

    // ---- output pointer ----
    u16* outp;
    int Tp, tbase;
    if (l < 15){
      outp = HC + ((size_t)me*RING + slot)*CHSZ;
      Tp = CL; tbase = 0;
    } else {
      outp = HS15 + (size_t)s*16*384*128;
      Tp = 384; tbase = t0;
    }

    // ---- scan in 4-step windows: pre-GEMM x-projections, then h-recurrence ----
    for (int q = 0; q < 4; ++q){
      // pre-GEMM: xp = bias + x@K for 4 steps (independent 4-deep MFMA chains)
      f32x4 xpz[4], xpr[4], xph[4];
      #pragma unroll
      for (int t2 = 0; t2 < 4; ++t2){
        int tt = q*4 + t2;
        short8 ax[4];
        #pragma unroll
        for (int ks = 0; ks < 4; ++ks){
          int xb = (((lr*CL + tt)*128 + ks*32 + lg*8) << 1) ^ ((lr&7)<<4);
          ax[ks] = *(const short8*)((char*)xs + xb);
        }
        f32x4 az  = {bz, bz, bz, bz};
        f32x4 ar  = {br_, br_, br_, br_};
        f32x4 ahx = {bhx, bhx, bhx, bhx};
        #pragma unroll
        for (int ks = 0; ks < 4; ++ks){
          az  = mfma16(ax[ks], wz[4+ks],  az);
          ar  = mfma16(ax[ks], wr2[4+ks], ar);
          ahx = mfma16(ax[ks], whx[ks],   ahx);
        }
        xpz[t2] = az; xpr[t2] = ar; xph[t2] = ahx;
      }
      // serial steps: h-recurrence only (4 ds_read + three 4-deep chains + gates)
      #pragma unroll
      for (int t2 = 0; t2 < 4; ++t2){
        int tt = q*4 + t2;
        int hp = tt & 1;
        short8 ah[4];
        #pragma unroll
        for (int ks = 0; ks < 4; ++ks){
          int hb = hp*4096 + (((lr*128 + ks*32 + lg*8) << 1) ^ ((lr&7)<<4));
          ah[ks] = *(const short8*)((char*)hs2 + hb);
        }
        f32x4 az  = xpz[t2];
        f32x4 ar  = xpr[t2];
        f32x4 ahr = {bhr, bhr, bhr, bhr};
        #pragma unroll
        for (int ks = 0; ks < 4; ++ks){
          az  = mfma16(ah[ks], wz[ks],  az);
          ar  = mfma16(ah[ks], wr2[ks], ar);
          ahr = mfma16(ah[ks], whr[ks], ahr);
        }
        // gates (acc layout: col=lr -> j, row=lg*4+r -> b)
        int j = wv*16 + lr;
        #pragma unroll
        for (int r = 0; r < 4; ++r){
          int b = lg*4 + r;
          float z  = 1.f/(1.f + __expf(-az[r]));
          float rg = 1.f/(1.f + __expf(-ar[r]));
          float pre = xph[t2][r] + rg*ahr[r];
          pre = fminf(fmaxf(pre, -15.f), 15.f);
          float e2 = __expf(2.f*pre);
          float hh = (e2 - 1.f)/(e2 + 1.f);
          float hn = z*hreg[r] + (1.f - z)*hh;
          hreg[r] = hn;
          u16 hb16 = f2bf(hn);
          int byte = ((hp^1)*4096) + ((((b*128 + j) << 1)) ^ ((b&7)<<4));
          *(u16*)((char*)hs2 + byte) = hb16;
          outp[((size_t)b*Tp + tbase + tt)*128 + j] = hb16;
        }
        __syncthreads();
      }
    }

    // ---- publish chunk (release: L2 writeback + flag) ----
    if (l < 15 && tid == 0){
      __hip_atomic_fetch_add(&prodF[me*32], 1u, __ATOMIC_RELEASE, __HIP_MEMORY_SCOPE_AGENT);
    }
  }
}

// ---------------- FF hidden pass: S[part][b][f] += sum_t relu(x@W1+b1) ----------------
__global__ __launch_bounds__(256) void k_ffs(const u16* __restrict__ HS, const u16* __restrict__ W1t,
                                             const float* __restrict__ b1, float* __restrict__ S){
  int bid = blockIdx.x;
  int part = bid / 384; int rem = bid % 384;
  int b = rem / 24; int rem2 = rem % 24;
  int t0 = (rem2 / 4) * 64, c0 = (rem2 % 4) * 256;
  int tid = threadIdx.x, lane = tid & 63, wid = tid >> 6, lr = lane & 15, lg = lane >> 4;
  int sA = part ? 1 : 0, sB = part ? 2 : 3;
  float sgn = part ? 1.f : -1.f;
  short8 af[4][4];
  #pragma unroll
  for (int rt = 0; rt < 4; ++rt)
    #pragma unroll
    for (int ks = 0; ks < 4; ++ks){
      size_t i1 = (((size_t)sA*16 + b)*384 + t0 + rt*16 + lr)*128 + ks*32 + lg*8;
      size_t i2 = (((size_t)sB*16 + b)*384 + t0 + rt*16 + lr)*128 + ks*32 + lg*8;
      short8 va = *(const short8*)(HS + i1);
      short8 vb = *(const short8*)(HS + i2);
      short8 o;
      #pragma unroll
      for (int e = 0; e < 8; ++e){
        float f = bf2f((u16)va[e]) + sgn*bf2f((u16)vb[e]);
        o[e] = (short)f2bf(f);
      }
      af[rt][ks] = o;
    }
  for (int ctl = 0; ctl < 4; ++ctl){
    int col = c0 + wid*64 + ctl*16 + lr;
    short8 bf[4];
    #pragma unroll
    for (int ks = 0; ks < 4; ++ks)
      bf[ks] = *(const short8*)(W1t + (size_t)col*128 + ks*32 + lg*8);
    float bias = b1[col];
    float ssum = 0.f;
    #pragma unroll
    for (int rt = 0; rt < 4; ++rt){
      f32x4 acc = {0,0,0,0};
      #pragma unroll
      for (int ks = 0; ks < 4; ++ks) acc = mfma16(af[rt][ks], bf[ks], acc);
      #pragma unroll
      for (int r = 0; r < 4; ++r) ssum += fmaxf(acc[r] + bias, 0.f);
    }
    ssum += __shfl_xor(ssum, 16, 64);
    ssum += __shfl_xor(ssum, 32, 64);
    if (lg == 0) atomicAdd(&S[((size_t)part*16 + b)*1024 + col], ssum);
  }
}

// ---------------- sum over t of last-layer activations (4-way t-split) ----------------
__global__ void k_mx(const u16* __restrict__ HS, float* __restrict__ Mx){
  int bid = blockIdx.x; int u = threadIdx.x;
  int pb = bid >> 2, tq = bid & 3;
  int p = pb >> 4, b = pb & 15;
  int sA = p ? 1 : 0, sB = p ? 2 : 3;
  float sgn = p ? 1.f : -1.f;
  float s = 0.f;
  for (int t = tq*96; t < tq*96 + 96; ++t){
    float a = bf2f(HS[(((size_t)sA*16 + b)*384 + t)*128 + u]);
    float c = bf2f(HS[(((size_t)sB*16 + b)*384 + t)*128 + u]);
    s += a + sgn*c;
  }
  atomicAdd(&Mx[pb*128 + u], s);
}

// ---------------- combine: M = Mx/384 + (S@W2)/384 + b2 ----------------
__global__ void k_comb(const float* __restrict__ S, const float* __restrict__ Mx,
                       const float* __restrict__ w2, const float* __restrict__ b2,
                       float* __restrict__ M){
  int pb = blockIdx.x; int u = threadIdx.x;
  const float* Sp = S + (size_t)pb*1024;
  float acc = 0.f;
  for (int f = 0; f < 1024; ++f) acc += Sp[f] * w2[(size_t)f*128 + u];
  M[pb*128 + u] = Mx[pb*128 + u] * (1.f/384.f) + acc * (1.f/384.f) + b2[u];
}

// ---------------- Q/R heads (f32) + sum|Q|^2 ----------------
__global__ __launch_bounds__(256) void k_qr(const float* __restrict__ M,
    const float* __restrict__ qr_w, const float* __restrict__ qr_b,
    const float* __restrict__ qi_w, const float* __restrict__ qi_b,
    const float* __restrict__ rr_w, const float* __restrict__ rr_b,
    const float* __restrict__ ri_w, const float* __restrict__ ri_b,
    float* __restrict__ out, float* __restrict__ ssq){
  __shared__ float smr[128], smi[128];
  int bid = blockIdx.x; int tid = threadIdx.x;
  int b = bid >> 4; int o = (bid & 15)*256 + tid;
  if (tid < 128){ smr[tid] = M[b*128 + tid]; smi[tid] = M[(16 + b)*128 + tid]; }
  __syncthreads();
  float aq=0, bq=0, cq=0, dq=0, ar=0, br2=0, cr=0, dr=0;
  for (int u = 0; u < 128; ++u){
    float mr = smr[u], mi = smi[u];
    float wqr = qr_w[(size_t)u*4096 + o], wqi = qi_w[(size_t)u*4096 + o];
    float wrr = rr_w[(size_t)u*4096 + o], wri = ri_w[(size_t)u*4096 + o];
    aq += mr*wqr;  bq += mi*wqi;  cq += mi*wqr;  dq += mr*wqi;
    ar += mr*wrr;  br2 += mi*wri; cr += mi*wrr;  dr += mr*wri;
  }
  float Qr = (aq + qr_b[o]) - (bq + qi_b[o]);
  float Qi = (cq + qr_b[o]) + (dq + qi_b[o]);
  float Rr = (ar + rr_b[o]) - (br2 + ri_b[o]);
  float Ri = (cr + rr_b[o]) + (dr + ri_b[o]);
  out[(size_t)b*4096 + o] = Qr;
  out[65536 + (size_t)b*4096 + o] = Qi;
  out[131072 + (size_t)b*4096 + o] = Rr;
  out[196608 + (size_t)b*4096 + o] = Ri;
  float ss = Qr*Qr + Qi*Qi;
  for (int off = 32; off; off >>= 1) ss += __shfl_down(ss, off, 64);
  if ((tid & 63) == 0) atomicAdd(&ssq[b], ss);
}

// ---------------- scale Q by sqrt(N)/nrm ----------------
__global__ void k_scale(float* __restrict__ out, const float* __restrict__ ssq){
  int i = blockIdx.x*256 + threadIdx.x;   // covers Qr and Qi regions: 131072
  int b = (i >> 12) & 15;
  float s = 8.f / sqrtf(ssq[b]);
  out[i] *= s;
}

extern "C" void kernel_launch(void* const* d_in, const int* in_sizes, int n_in,
                              void* d_out, int out_size, void* d_ws, size_t ws_size,
                              hipStream_t stream){
  const float* h_real = (const float*)d_in[0];
  const float* h_imag = (const float*)d_in[1];
  const float* conv_wr = (const float*)d_in[2];
  const float* conv_wi = (const float*)d_in[3];
  const float* bn_gr = (const float*)d_in[4];
  const float* bn_gi = (const float*)d_in[5];
  const float* bn_vr = (const float*)d_in[6];
  const float* bn_vi = (const float*)d_in[7];
  const float* bn_br = (const float*)d_in[8];
  const float* bn_bi = (const float*)d_in[9];
  const float* bn_mr = (const float*)d_in[10];
  const float* bn_mi = (const float*)d_in[11];
  const float* g0_kr = (const float*)d_in[12];
  const float* g0_rkr = (const float*)d_in[13];
  const float* g0_br = (const float*)d_in[14];
  const float* g0_ki = (const float*)d_in[15];
  const float* g0_rki = (const float*)d_in[16];
  const float* g0_bi = (const float*)d_in[17];
  const float* gs_kr = (const float*)d_in[18];
  const float* gs_rkr = (const float*)d_in[19];
  const float* gs_br = (const float*)d_in[20];
  const float* gs_ki = (const float*)d_in[21];
  const float* gs_rki = (const float*)d_in[22];
  const float* gs_bi = (const float*)d_in[23];
  const float* ff1_w = (const float*)d_in[24];
  const float* ff1_b = (const float*)d_in[25];
  const float* ff2_w = (const float*)d_in[26];
  const float* ff2_b = (const float*)d_in[27];
  const float* qr_w = (const float*)d_in[28];
  const float* qr_b = (const float*)d_in[29];
  const float* qi_w = (const float*)d_in[30];
  const float* qi_b = (const float*)d_in[31];
  const float* rr_w = (const float*)d_in[32];
  const float* rr_b = (const float*)d_in[33];
  const float* ri_w = (const float*)d_in[34];
  const float* ri_b = (const float*)d_in[35];

  char* ws = (char*)d_ws; size_t off = 0;
  auto carve = [&](size_t bytes)->char*{ char* p = ws + off; off += (bytes + 255) & ~(size_t)255; return p; };
  u16* X0   = (u16*)carve((size_t)2*16*384*64*2);          // 1.5 MB
  u16* HC   = (u16*)carve((size_t)64*RING*CHSZ*2);         // 16.8 MB chunk ring
  u16* HS15 = (u16*)carve((size_t)4*16*384*128*2);         // 6.3 MB (layer-15 full-seq streams)
  u16* KT   = (u16*)carve((size_t)16*2*384*128*2);         // 3.1 MB
  u16* RKT  = (u16*)carve((size_t)16*2*384*128*2);         // 3.1 MB
  u16* WtR  = (u16*)carve(131072*2);
  u16* WtI  = (u16*)carve(131072*2);
  u16* WtIN = (u16*)carve(131072*2);
  u16* W1t  = (u16*)carve(131072*2);
  u32* Flg  = (u32*)carve(4096*4);                         // prod/cons flags (128B padded)
  float* S  = (float*)carve(32768*4);
  float* Mx = (float*)carve(4096*4);
  float* M  = (float*)carve(4096*4);
  float* ssq = (float*)carve(256);

  k_init<<<161, 256, 0, stream>>>(S, ssq, Flg, Mx);
  k_wprep<<<1024, 256, 0, stream>>>(conv_wr, conv_wi, ff1_w, WtR, WtI, WtIN, W1t);
  k_wprep2<<<768, 256, 0, stream>>>(g0_kr, g0_ki, gs_kr, gs_ki,
                                    g0_rkr, g0_rki, gs_rkr, gs_rki, KT, RKT);
  k_conv<<<192, 256, 0, stream>>>(h_real, h_imag, WtR, WtI, WtIN,
                                  bn_gr, bn_gi, bn_vr, bn_vi, bn_br, bn_bi, bn_mr, bn_mi, X0);
  k_scanp<<<64, 512, 0, stream>>>(X0, KT, RKT, g0_br, g0_bi, gs_br, gs_bi,
                                  HC, HS15, Flg);
  k_ffs<<<768, 256, 0, stream>>>(HS15, W1t, ff1_b, S);
  k_mx<<<128, 128, 0, stream>>>(HS15, Mx);
  k_comb<<<32, 128, 0, stream>>>(S, Mx, ff2_w, ff2_b, M);
  k_qr<<<256, 256, 0, stream>>>(M, qr_w, qr_b, qi_w, qi_b, rr_w, rr_b, ri_w, ri_b,
                                (float*)d_out, ssq);
  k_scale<<<512, 256, 0, stream>>>((float*)d_out, ssq);
}

// Round 15
// 1063.469 us; speedup vs baseline: 1.0282x; 1.0282x over previous
//
#include <hip/hip_runtime.h>
#include <hip/hip_bf16.h>
#include <math.h>

typedef __attribute__((ext_vector_type(8))) short short8;
typedef __attribute__((ext_vector_type(4))) float f32x4;
typedef unsigned short u16;
typedef unsigned int u32;

#define CL 16              // chunk length (timesteps per handoff)
#define NCHUNK 24          // 384 / CL
#define RING 4             // ring depth per (layer,stream)
#define CHSZ (16*CL*128)   // u16 per chunk slot = 32768

__device__ __forceinline__ u16 f2bf(float f){
  u32 x = __float_as_uint(f);
  u32 r = x + 0x7fffu + ((x >> 16) & 1u);
  return (u16)(r >> 16);
}
__device__ __forceinline__ float bf2f(u16 u){
  return __uint_as_float(((u32)u) << 16);
}
__device__ __forceinline__ f32x4 mfma16(short8 a, short8 b, f32x4 c){
  return __builtin_amdgcn_mfma_f32_16x16x32_bf16(a, b, c, 0, 0, 0);
}

// ---------------- merged prologue: init + conv-weight prep + GRU-weight prep ----------------
// bid < 177          : zero S/ssq/Flg/Mx/Macc
// 177 <= bid < 1201  : conv weights [k][f][c] bf16 + W1 transpose
// 1201 <= bid < 1969 : GRU weight transpose (LDS-tiled)
__global__ __launch_bounds__(256) void k_pro(
    float* S, float* ssq, u32* Flg, float* Mx, float* Macc,
    const float* __restrict__ wr, const float* __restrict__ wi,
    const float* __restrict__ w1,
    u16* WtR, u16* WtI, u16* WtIN, u16* W1t,
    const float* __restrict__ g0_kr, const float* __restrict__ g0_ki,
    const float* __restrict__ gs_kr, const float* __restrict__ gs_ki,
    const float* __restrict__ g0_rkr, const float* __restrict__ g0_rki,
    const float* __restrict__ gs_rkr, const float* __restrict__ gs_rki,
    u16* __restrict__ KT, u16* __restrict__ RKT){
  __shared__ float tile[128][33];
  int bid = blockIdx.x, tid = threadIdx.x;
  if (bid < 177){
    int i = bid*256 + tid;
    if (i < 32768){ S[i] = 0.f; return; }
    i -= 32768;
    if (i < 16){ ssq[i] = 0.f; return; }
    i -= 16;
    if (i < 4096){ Flg[i] = 0u; return; }
    i -= 4096;
    if (i < 4096){ Mx[i] = 0.f; return; }
    i -= 4096;
    if (i < 4096){ Macc[i] = 0.f; return; }
    return;
  }
  if (bid < 1201){
    int i = (bid - 177)*256 + tid;
    if (i < 131072){
      int k = i >> 12, r = i & 4095, f = r >> 6, c = r & 63;
      float a = wr[(k<<12) + (c<<6) + f];
      float b = wi[(k<<12) + (c<<6) + f];
      WtR[i] = f2bf(a); WtI[i] = f2bf(b); WtIN[i] = f2bf(-b);
    } else {
      int j = i - 131072;           // j = col*128 + k ;  W1t[col][k] = w1[k][col]
      int col = j >> 7, k = j & 127;
      W1t[j] = f2bf(w1[(k<<10) + col]);
    }
    return;
  }
  {
    int bid2 = bid - 1201;
    int ct = bid2 % 12; int lm = (bid2/12) & 31; int which = bid2 / (12*32);
    int m = lm & 1, l = lm >> 1;
    int c0 = ct*32;
    for (int idx = tid; idx < 128*32; idx += 256){
      int k = idx >> 5, cc = idx & 31;
      float v;
      if (!which){
        if (l == 0) v = (k < 64) ? (m ? g0_ki : g0_kr)[k*384 + c0+cc] : 0.f;
        else        v = (m ? gs_ki : gs_kr)[((size_t)(l-1)*128 + k)*384 + c0+cc];
      } else {
        if (l == 0) v = (m ? g0_rki : g0_rkr)[k*384 + c0+cc];
        else        v = (m ? gs_rki : gs_rkr)[((size_t)(l-1)*128 + k)*384 + c0+cc];
      }
      tile[k][cc] = v;
    }
    __syncthreads();
    u16* dst = (which ? RKT : KT) + (size_t)lm*384*128;
    for (int idx = tid; idx < 32*128; idx += 256){
      int cc = idx >> 7, k = idx & 127;
      dst[(size_t)(c0+cc)*128 + k] = f2bf(tile[k][cc]);
    }
  }
}

// ---------------- conv1d (K=32, SAME padlow=15) + BN -> X0 bf16 [2][16][384][64] ----------------
// 32-wide t-tiles: two 16x16 output tiles share one staged window and one weight
// fetch (each weight fragment feeds 8 MFMAs). grid = 16 batches x 12 tiles.
__global__ __launch_bounds__(256) void k_conv(
    const float* __restrict__ hr, const float* __restrict__ hi,
    const u16* __restrict__ WtR, const u16* __restrict__ WtI, const u16* __restrict__ WtIN,
    const float* __restrict__ gr, const float* __restrict__ gi,
    const float* __restrict__ vr, const float* __restrict__ vi,
    const float* __restrict__ br, const float* __restrict__ bi,
    const float* __restrict__ mr, const float* __restrict__ mi,
    u16* __restrict__ X0){
  __shared__ u16 xst[2*64*64];      // [part][row 0..62][c]; row = t - t0 + 15
  int tid = threadIdx.x;
  int bid = blockIdx.x;
  int b = bid / 12, t0 = (bid % 12) * 32;
  for (int el = tid; el < 2*63*64; el += 256){
    int part = el / (63*64); int rem = el % (63*64); int row = rem >> 6; int c = rem & 63;
    int tg = t0 + row - 15;
    const float* src = part ? hi : hr;
    float v = (tg >= 0 && tg < 384) ? src[((size_t)b*384 + tg)*64 + c] : 0.f;
    int idx = (part*64 + row)*64 + c;
    int byte = (idx<<1) ^ ((row&7)<<4);
    *(u16*)((char*)xst + byte) = f2bf(v);
  }
  __syncthreads();
  int lane = tid & 63, wid = tid >> 6, lr = lane & 15, lg = lane >> 4;
  f32x4 accr = {0,0,0,0}, acci = {0,0,0,0};
  f32x4 accr2 = {0,0,0,0}, acci2 = {0,0,0,0};
  for (int k = 0; k < 32; ++k){
    int row = lr + k;           // tile A rows [0,47)
    int row2 = row + 16;        // tile B rows [16,63)
    int swz = (row&7)<<4, swz2 = (row2&7)<<4;
    for (int ch = 0; ch < 2; ++ch){
      int c0 = ch*32 + lg*8;
      int idxr  = (0*64 + row )*64 + c0;
      int idxi  = (1*64 + row )*64 + c0;
      int idxr2 = (0*64 + row2)*64 + c0;
      int idxi2 = (1*64 + row2)*64 + c0;
      short8 ar  = *(const short8*)((const char*)xst + ((idxr <<1) ^ swz));
      short8 ai  = *(const short8*)((const char*)xst + ((idxi <<1) ^ swz));
      short8 ar2 = *(const short8*)((const char*)xst + ((idxr2<<1) ^ swz2));
      short8 ai2 = *(const short8*)((const char*)xst + ((idxi2<<1) ^ swz2));
      size_t wb = ((size_t)(k*64 + wid*16 + lr))*64 + c0;
      short8 bwr = *(const short8*)(WtR + wb);
      short8 bwi = *(const short8*)(WtI + wb);
      short8 bwn = *(const short8*)(WtIN + wb);
      accr  = mfma16(ar,  bwr, accr);
      accr  = mfma16(ai,  bwn, accr);
      acci  = mfma16(ai,  bwr, acci);
      acci  = mfma16(ar,  bwi, acci);
      accr2 = mfma16(ar2, bwr, accr2);
      accr2 = mfma16(ai2, bwn, accr2);
      acci2 = mfma16(ai2, bwr, acci2);
      acci2 = mfma16(ar2, bwi, acci2);
    }
  }
  int f = wid*16 + lr;
  float sr_ = gr[f] * rsqrtf(vr[f] + 1e-3f), or_ = br[f] - mr[f]*sr_;
  float si_ = gi[f] * rsqrtf(vi[f] + 1e-3f), oi_ = bi[f] - mi[f]*si_;
  for (int r = 0; r < 4; ++r){
    int t  = t0 + lg*4 + r;
    int t2 = t0 + 16 + lg*4 + r;
    X0[(((size_t)0*16 + b)*384 + t )*64 + f] = f2bf(accr[r] *sr_ + or_);
    X0[(((size_t)1*16 + b)*384 + t )*64 + f] = f2bf(acci[r] *si_ + oi_);
    X0[(((size_t)0*16 + b)*384 + t2)*64 + f] = f2bf(accr2[r]*sr_ + or_);
    X0[(((size_t)1*16 + b)*384 + t2)*64 + f] = f2bf(acci2[r]*si_ + oi_);
  }
}

// ---------------- persistent dataflow GRU scan (R7 protocol, R14-green, untouched) ----------------
__global__ __launch_bounds__(512,1) void k_scanp(
    const u16* __restrict__ X0, const u16* __restrict__ KT, const u16* __restrict__ RKT,
    const float* __restrict__ g0_br, const float* __restrict__ g0_bi,
    const float* __restrict__ gs_br, const float* __restrict__ gs_bi,
    u16* __restrict__ HC, u16* __restrict__ HS15, u32* Flg)
{
  int bid = blockIdx.x;
  int l = bid >> 2, s = bid & 3;

  __shared__ u16 xs[16*CL*128];     // 64KB staged x chunk (swizzled)
  __shared__ u16 hs2[2*16*128];     // 8KB double-buffered h (bf16, swizzled)
  __shared__ float bsh[4][128];     // folded biases: z(b0+b1), r(b0+b1), hx(b0), hr(b1)

  int tid = threadIdx.x, lane = tid & 63, wv = tid >> 6, lr = lane & 15, lg = lane >> 4;
  int m = s >> 1;

  // --- bias fold ---
  const float* Bsrc = (l == 0) ? (m ? g0_bi : g0_br)
                               : ((m ? gs_bi : gs_br) + (size_t)(l-1)*768);
  if (tid < 128){
    int j = tid;
    bsh[0][j] = Bsrc[j]       + Bsrc[384 + j];
    bsh[1][j] = Bsrc[128 + j] + Bsrc[384 + 128 + j];
    bsh[2][j] = Bsrc[256 + j];
    bsh[3][j] = Bsrc[384 + 256 + j];
  }
  // zero h LDS (both parities); bf16 0x0000 == 0.0
  for (int i = tid; i < 2048; i += 512) ((u32*)hs2)[i] = 0u;

  // --- weight fragments into registers (24 short8 per thread, once) ---
  const u16* Kp  = KT  + (size_t)(l*2 + m)*384*128;
  const u16* RKp = RKT + (size_t)(l*2 + m)*384*128;
  int cz = wv*16 + lr;
  short8 wz[8], wr2[8], whx[4], whr[4];
  #pragma unroll
  for (int ks = 0; ks < 4; ++ks){
    wz[ks]    = *(const short8*)(RKp + (size_t)cz*128 + ks*32 + lg*8);
    wz[4+ks]  = *(const short8*)(Kp  + (size_t)cz*128 + ks*32 + lg*8);
    wr2[ks]   = *(const short8*)(RKp + (size_t)(128+cz)*128 + ks*32 + lg*8);
    wr2[4+ks] = *(const short8*)(Kp  + (size_t)(128+cz)*128 + ks*32 + lg*8);
    whx[ks]   = *(const short8*)(Kp  + (size_t)(256+cz)*128 + ks*32 + lg*8);
    whr[ks]   = *(const short8*)(RKp + (size_t)(256+cz)*128 + ks*32 + lg*8);
  }

  float hreg[4] = {0.f, 0.f, 0.f, 0.f};

  __syncthreads();
  float bz, br_, bhx, bhr;
  {
    int j = wv*16 + lr;
    bz = bsh[0][j]; br_ = bsh[1][j]; bhx = bsh[2][j]; bhr = bsh[3][j];
  }

  u32* prodF = Flg;              // prod[i] at Flg[i*32]   (128B padded)
  u32* consF = Flg + 2048;       // cons[i] at Flg[2048+i*32]
  int sA = (s & 1) ? 1 : 0, sB = (s & 1) ? 2 : 3;
  int pA = (l-1)*4 + sA, pB = (l-1)*4 + sB;   // only used when l>0
  float sgn = (s & 1) ? 1.f : -1.f;
  int p = s & 1;                 // X0 part for l==0
  int me = l*4 + s;

  for (int c = 0; c < NCHUNK; ++c){
    int t0 = c * CL;
    int slot = c & (RING-1);

    // ---- waits (tid0 spins; others park at the barrier) ----
    if (tid == 0){
      int guard = 0;
      if (l > 0){
        while (__hip_atomic_load(&prodF[pA*32], __ATOMIC_RELAXED, __HIP_MEMORY_SCOPE_AGENT) < (u32)(c+1) ||
               __hip_atomic_load(&prodF[pB*32], __ATOMIC_RELAXED, __HIP_MEMORY_SCOPE_AGENT) < (u32)(c+1)){
          __builtin_amdgcn_s_sleep(1);
          if (++guard > 10000000) break;   // hang-avoid bailout
        }
      }
      if (l < 15 && c >= RING){           // ring backpressure: both consumers done with c-RING
        guard = 0;
        while (__hip_atomic_load(&consF[me*32], __ATOMIC_RELAXED, __HIP_MEMORY_SCOPE_AGENT) < (u32)(2*(c-RING+1))){
          __builtin_amdgcn_s_sleep(1);
          if (++guard > 10000000) break;
        }
      }
    }
    __syncthreads();

    // ---- stage x chunk into LDS (element = b(4b)|ttv(4b)|k8(4b), b = g>>8) ----
    if (l == 0){
      short8 v[8];
      #pragma unroll
      for (int it = 0; it < 8; ++it){
        int g = tid + it*512;
        int k8 = g & 15, ttv = (g>>4) & 15, b = g >> 8;
        short8 t = {0,0,0,0,0,0,0,0};
        if (k8 < 8) t = *(const short8*)(X0 + (((size_t)p*16 + b)*384 + t0 + ttv)*64 + k8*8);
        v[it] = t;
      }
      asm volatile("" ::: "memory");
      #pragma unroll
      for (int it = 0; it < 8; ++it){
        int g = tid + it*512;
        int k8 = g & 15, ttv = (g>>4) & 15, b = g >> 8;
        int byte = (((b*CL + ttv)*128 + k8*8) << 1) ^ ((b&7)<<4);
        *(short8*)((char*)xs + byte) = v[it];
      }
      __syncthreads();
    } else {
      // make producers' chunk data visible (cross-XCD: buffer_inv)
      __builtin_amdgcn_fence(__ATOMIC_ACQUIRE, "agent");
      const u16* baseA = HC + ((size_t)pA*RING + slot)*CHSZ;
      const u16* baseB = HC + ((size_t)pB*RING + slot)*CHSZ;
      short8 va[8], vb[8];
      #pragma unroll
      for (int it = 0; it < 8; ++it){
        int g = tid + it*512;
        int k8 = g & 15, ttv = (g>>4) & 15, b = g >> 8;
        size_t si = ((size_t)b*CL + ttv)*128 + k8*8;
        va[it] = *(const short8*)(baseA + si);
        vb[it] = *(const short8*)(baseB + si);
      }
      asm volatile("" ::: "memory");
      #pragma unroll
      for (int it = 0; it < 8; ++it){
        int g = tid + it*512;
        int k8 = g & 15, ttv = (g>>4) & 15, b = g >> 8;
        short8 o;
        #pragma unroll
        for (int e = 0; e < 8; ++e){
          float f = bf2f((u16)va[it][e]) + sgn*bf2f((u16)vb[it][e]);
          o[e] = (short)f2bf(f);
        }
        int byte = (((b*CL + ttv)*128 + k8*8) << 1) ^ ((b&7)<<4);
        *(short8*)((char*)xs + byte) = o;
      }
      __syncthreads();                    // all staging reads complete before signaling
      if (tid == 0){
        __hip_atomic_fetch_add(&consF[pA*32], 1u, __ATOMIC_RELAXED, __HIP_MEMORY_SCOPE_AGENT);
        __hip_atomic_fetch_add(&consF[pB*32], 1u, __ATOMIC_RELAXED, __HIP_MEMORY_SCOPE_AGENT);
      }
    }

    // ---- output pointer ----
    u16* outp;
    int Tp, tbase;
    if (l < 15){
      outp = HC + ((size_t)me*RING + slot)*CHSZ;
      Tp = CL; tbase = 0;
    } else {
      outp = HS15 + (size_t)s*16*384*128;
      Tp = 384; tbase = t0;
    }

    // ---- scan in 4-step windows: pre-GEMM x-projections, then h-recurrence ----
    for (int q = 0; q < 4; ++q){
      // pre-GEMM: xp = bias + x@K for 4 steps (independent 4-deep MFMA chains)
      f32x4 xpz[4], xpr[4], xph[4];
      #pragma unroll
      for (int t2 = 0; t2 < 4; ++t2){
        int tt = q*4 + t2;
        short8 ax[4];
        #pragma unroll
        for (int ks = 0; ks < 4; ++ks){
          int xb = (((lr*CL + tt)*128 + ks*32 + lg*8) << 1) ^ ((lr&7)<<4);
          ax[ks] = *(const short8*)((char*)xs + xb);
        }
        f32x4 az  = {bz, bz, bz, bz};
        f32x4 ar  = {br_, br_, br_, br_};
        f32x4 ahx = {bhx, bhx, bhx, bhx};
        #pragma unroll
        for (int ks = 0; ks < 4; ++ks){
          az  = mfma16(ax[ks], wz[4+ks],  az);
          ar  = mfma16(ax[ks], wr2[4+ks], ar);
          ahx = mfma16(ax[ks], whx[ks],   ahx);
        }
        xpz[t2] = az; xpr[t2] = ar; xph[t2] = ahx;
      }
      // serial steps: h-recurrence only (4 ds_read + three 4-deep chains + gates)
      #pragma unroll
      for (int t2 = 0; t2 < 4; ++t2){
        int tt = q*4 + t2;
        int hp = tt & 1;
        short8 ah[4];
        #pragma unroll
        for (int ks = 0; ks < 4; ++ks){
          int hb = hp*4096 + (((lr*128 + ks*32 + lg*8) << 1) ^ ((lr&7)<<4));
          ah[ks] = *(const short8*)((char*)hs2 + hb);
        }
        f32x4 az  = xpz[t2];
        f32x4 ar  = xpr[t2];
        f32x4 ahr = {bhr, bhr, bhr, bhr};
        #pragma unroll
        for (int ks = 0; ks < 4; ++ks){
          az  = mfma16(ah[ks], wz[ks],  az);
          ar  = mfma16(ah[ks], wr2[ks], ar);
          ahr = mfma16(ah[ks], whr[ks], ahr);
        }
        // gates (acc layout: col=lr -> j, row=lg*4+r -> b)
        int j = wv*16 + lr;
        #pragma unroll
        for (int r = 0; r < 4; ++r){
          int b = lg*4 + r;
          float z  = 1.f/(1.f + __expf(-az[r]));
          float rg = 1.f/(1.f + __expf(-ar[r]));
          float pre = xph[t2][r] + rg*ahr[r];
          pre = fminf(fmaxf(pre, -15.f), 15.f);
          float e2 = __expf(2.f*pre);
          float hh = (e2 - 1.f)/(e2 + 1.f);
          float hn = z*hreg[r] + (1.f - z)*hh;
          hreg[r] = hn;
          u16 hb16 = f2bf(hn);
          int byte = ((hp^1)*4096) + ((((b*128 + j) << 1)) ^ ((b&7)<<4));
          *(u16*)((char*)hs2 + byte) = hb16;
          outp[((size_t)b*Tp + tbase + tt)*128 + j] = hb16;
        }
        __syncthreads();
      }
    }

    // ---- publish chunk (release: L2 writeback + flag) ----
    if (l < 15 && tid == 0){
      __hip_atomic_fetch_add(&prodF[me*32], 1u, __ATOMIC_RELEASE, __HIP_MEMORY_SCOPE_AGENT);
    }
  }
}

// ---------------- FF hidden pass + fused mean-pool partials ----------------
// S[part][b][f] += sum_t relu(x@W1+b1); c0==0 blocks' wave 0 also reduce the
// combined af values (the exact data k_mx used to re-read) into Mx.
__global__ __launch_bounds__(256) void k_ffs(const u16* __restrict__ HS, const u16* __restrict__ W1t,
                                             const float* __restrict__ b1, float* __restrict__ S,
                                             float* __restrict__ Mx){
  int bid = blockIdx.x;
  int part = bid / 384; int rem = bid % 384;
  int b = rem / 24; int rem2 = rem % 24;
  int t0 = (rem2 / 4) * 64, c0 = (rem2 % 4) * 256;
  int tid = threadIdx.x, lane = tid & 63, wid = tid >> 6, lr = lane & 15, lg = lane >> 4;
  int sA = part ? 1 : 0, sB = part ? 2 : 3;
  float sgn = part ? 1.f : -1.f;
  short8 af[4][4];
  #pragma unroll
  for (int rt = 0; rt < 4; ++rt)
    #pragma unroll
    for (int ks = 0; ks < 4; ++ks){
      size_t i1 = (((size_t)sA*16 + b)*384 + t0 + rt*16 + lr)*128 + ks*32 + lg*8;
      size_t i2 = (((size_t)sB*16 + b)*384 + t0 + rt*16 + lr)*128 + ks*32 + lg*8;
      short8 va = *(const short8*)(HS + i1);
      short8 vb = *(const short8*)(HS + i2);
      short8 o;
      #pragma unroll
      for (int e = 0; e < 8; ++e){
        float f = bf2f((u16)va[e]) + sgn*bf2f((u16)vb[e]);
        o[e] = (short)f2bf(f);
      }
      af[rt][ks] = o;
    }
  // fused k_mx: one block per (part,b,t0) (c0==0), wave 0 only; af holds the
  // combined values for t in [t0,t0+64), u = ks*32+lg*8+e.
  if (rem2 % 4 == 0 && wid == 0){
    #pragma unroll
    for (int ks = 0; ks < 4; ++ks){
      #pragma unroll
      for (int e = 0; e < 8; ++e){
        float s = 0.f;
        #pragma unroll
        for (int rt = 0; rt < 4; ++rt) s += bf2f((u16)af[rt][ks][e]);
        s += __shfl_xor(s, 1, 64);
        s += __shfl_xor(s, 2, 64);
        s += __shfl_xor(s, 4, 64);
        s += __shfl_xor(s, 8, 64);
        if (lr == 0) atomicAdd(&Mx[((size_t)part*16 + b)*128 + ks*32 + lg*8 + e], s);
      }
    }
  }
  for (int ctl = 0; ctl < 4; ++ctl){
    int col = c0 + wid*64 + ctl*16 + lr;
    short8 bf[4];
    #pragma unroll
    for (int ks = 0; ks < 4; ++ks)
      bf[ks] = *(const short8*)(W1t + (size_t)col*128 + ks*32 + lg*8);
    float bias = b1[col];
    float ssum = 0.f;
    #pragma unroll
    for (int rt = 0; rt < 4; ++rt){
      f32x4 acc = {0,0,0,0};
      #pragma unroll
      for (int ks = 0; ks < 4; ++ks) acc = mfma16(af[rt][ks], bf[ks], acc);
      #pragma unroll
      for (int r = 0; r < 4; ++r) ssum += fmaxf(acc[r] + bias, 0.f);
    }
    ssum += __shfl_xor(ssum, 16, 64);
    ssum += __shfl_xor(ssum, 32, 64);
    if (lg == 0) atomicAdd(&S[((size_t)part*16 + b)*1024 + col], ssum);
  }
}

// ---------------- combine partials: Macc[pb][u] += sum_{f in quarter} S[f]*w2[f][u] ----------------
__global__ void k_combp(const float* __restrict__ S, const float* __restrict__ w2,
                        float* __restrict__ Macc){
  int bid = blockIdx.x; int u = threadIdx.x;
  int pb = bid >> 2, fq = bid & 3;
  const float* Sp = S + (size_t)pb*1024;
  float acc = 0.f;
  for (int f = fq*256; f < fq*256 + 256; ++f) acc += Sp[f] * w2[(size_t)f*128 + u];
  atomicAdd(&Macc[pb*128 + u], acc);
}

// ---------------- Q/R heads (f32) + sum|Q|^2 (folds M = (Mx+Macc)/384 + b2) ----------------
__global__ __launch_bounds__(256) void k_qr(const float* __restrict__ Mx,
    const float* __restrict__ Macc, const float* __restrict__ b2,
    const float* __restrict__ qr_w, const float* __restrict__ qr_b,
    const float* __restrict__ qi_w, const float* __restrict__ qi_b,
    const float* __restrict__ rr_w, const float* __restrict__ rr_b,
    const float* __restrict__ ri_w, const float* __restrict__ ri_b,
    float* __restrict__ out, float* __restrict__ ssq){
  __shared__ float smr[128], smi[128];
  int bid = blockIdx.x; int tid = threadIdx.x;
  int b = bid >> 4; int o = (bid & 15)*256 + tid;
  if (tid < 128){
    smr[tid] = (Mx[b*128 + tid]        + Macc[b*128 + tid]       ) * (1.f/384.f) + b2[tid];
    smi[tid] = (Mx[(16 + b)*128 + tid] + Macc[(16 + b)*128 + tid]) * (1.f/384.f) + b2[tid];
  }
  __syncthreads();
  float aq=0, bq=0, cq=0, dq=0, ar=0, br2=0, cr=0, dr=0;
  for (int u = 0; u < 128; ++u){
    float mr = smr[u], mi = smi[u];
    float wqr = qr_w[(size_t)u*4096 + o], wqi = qi_w[(size_t)u*4096 + o];
    float wrr = rr_w[(size_t)u*4096 + o], wri = ri_w[(size_t)u*4096 + o];
    aq += mr*wqr;  bq += mi*wqi;  cq += mi*wqr;  dq += mr*wqi;
    ar += mr*wrr;  br2 += mi*wri; cr += mi*wrr;  dr += mr*wri;
  }
  float Qr = (aq + qr_b[o]) - (bq + qi_b[o]);
  float Qi = (cq + qr_b[o]) + (dq + qi_b[o]);
  float Rr = (ar + rr_b[o]) - (br2 + ri_b[o]);
  float Ri = (cr + rr_b[o]) + (dr + ri_b[o]);
  out[(size_t)b*4096 + o] = Qr;
  out[65536 + (size_t)b*4096 + o] = Qi;
  out[131072 + (size_t)b*4096 + o] = Rr;
  out[196608 + (size_t)b*4096 + o] = Ri;
  float ss = Qr*Qr + Qi*Qi;
  for (int off = 32; off; off >>= 1) ss += __shfl_down(ss, off, 64);
  if ((tid & 63) == 0) atomicAdd(&ssq[b], ss);
}

// ---------------- scale Q by sqrt(N)/nrm ----------------
__global__ void k_scale(float* __restrict__ out, const float* __restrict__ ssq){
  int i = blockIdx.x*256 + threadIdx.x;   // covers Qr and Qi regions: 131072
  int b = (i >> 12) & 15;
  float s = 8.f / sqrtf(ssq[b]);
  out[i] *= s;
}

extern "C" void kernel_launch(void* const* d_in, const int* in_sizes, int n_in,
                              void* d_out, int out_size, void* d_ws, size_t ws_size,
                              hipStream_t stream){
  const float* h_real = (const float*)d_in[0];
  const float* h_imag = (const float*)d_in[1];
  const float* conv_wr = (const float*)d_in[2];
  const float* conv_wi = (const float*)d_in[3];
  const float* bn_gr = (const float*)d_in[4];
  const float* bn_gi = (const float*)d_in[5];
  const float* bn_vr = (const float*)d_in[6];
  const float* bn_vi = (const float*)d_in[7];
  const float* bn_br = (const float*)d_in[8];
  const float* bn_bi = (const float*)d_in[9];
  const float* bn_mr = (const float*)d_in[10];
  const float* bn_mi = (const float*)d_in[11];
  const float* g0_kr = (const float*)d_in[12];
  const float* g0_rkr = (const float*)d_in[13];
  const float* g0_br = (const float*)d_in[14];
  const float* g0_ki = (const float*)d_in[15];
  const float* g0_rki = (const float*)d_in[16];
  const float* g0_bi = (const float*)d_in[17];
  const float* gs_kr = (const float*)d_in[18];
  const float* gs_rkr = (const float*)d_in[19];
  const float* gs_br = (const float*)d_in[20];
  const float* gs_ki = (const float*)d_in[21];
  const float* gs_rki = (const float*)d_in[22];
  const float* gs_bi = (const float*)d_in[23];
  const float* ff1_w = (const float*)d_in[24];
  const float* ff1_b = (const float*)d_in[25];
  const float* ff2_w = (const float*)d_in[26];
  const float* ff2_b = (const float*)d_in[27];
  const float* qr_w = (const float*)d_in[28];
  const float* qr_b = (const float*)d_in[29];
  const float* qi_w = (const float*)d_in[30];
  const float* qi_b = (const float*)d_in[31];
  const float* rr_w = (const float*)d_in[32];
  const float* rr_b = (const float*)d_in[33];
  const float* ri_w = (const float*)d_in[34];
  const float* ri_b = (const float*)d_in[35];

  char* ws = (char*)d_ws; size_t off = 0;
  auto carve = [&](size_t bytes)->char*{ char* p = ws + off; off += (bytes + 255) & ~(size_t)255; return p; };
  u16* X0   = (u16*)carve((size_t)2*16*384*64*2);          // 1.5 MB
  u16* HC   = (u16*)carve((size_t)64*RING*CHSZ*2);         // 16.8 MB chunk ring
  u16* HS15 = (u16*)carve((size_t)4*16*384*128*2);         // 6.3 MB (layer-15 full-seq streams)
  u16* KT   = (u16*)carve((size_t)16*2*384*128*2);         // 3.1 MB
  u16* RKT  = (u16*)carve((size_t)16*2*384*128*2);         // 3.1 MB
  u16* WtR  = (u16*)carve(131072*2);
  u16* WtI  = (u16*)carve(131072*2);
  u16* WtIN = (u16*)carve(131072*2);
  u16* W1t  = (u16*)carve(131072*2);
  u32* Flg  = (u32*)carve(4096*4);                         // prod/cons flags (128B padded)
  float* S  = (float*)carve(32768*4);
  float* Mx = (float*)carve(4096*4);
  float* Macc = (float*)carve(4096*4);
  float* ssq = (float*)carve(256);

  k_pro<<<1969, 256, 0, stream>>>(S, ssq, Flg, Mx, Macc,
                                  conv_wr, conv_wi, ff1_w, WtR, WtI, WtIN, W1t,
                                  g0_kr, g0_ki, gs_kr, gs_ki,
                                  g0_rkr, g0_rki, gs_rkr, gs_rki, KT, RKT);
  k_conv<<<192, 256, 0, stream>>>(h_real, h_imag, WtR, WtI, WtIN,
                                  bn_gr, bn_gi, bn_vr, bn_vi, bn_br, bn_bi, bn_mr, bn_mi, X0);
  k_scanp<<<64, 512, 0, stream>>>(X0, KT, RKT, g0_br, g0_bi, gs_br, gs_bi,
                                  HC, HS15, Flg);
  k_ffs<<<768, 256, 0, stream>>>(HS15, W1t, ff1_b, S, Mx);
  k_combp<<<128, 128, 0, stream>>>(S, ff2_w, Macc);
  k_qr<<<256, 256, 0, stream>>>(Mx, Macc, ff2_b, qr_w, qr_b, qi_w, qi_b,
                                rr_w, rr_b, ri_w, ri_b, (float*)d_out, ssq);
  k_scale<<<512, 256, 0, stream>>>((float*)d_out, ssq);
}

// Round 16
// 1060.524 us; speedup vs baseline: 1.0310x; 1.0028x over previous
//
#include <hip/hip_runtime.h>
#include <hip/hip_bf16.h>
#include <math.h>

typedef __attribute__((ext_vector_type(8))) short short8;
typedef __attribute__((ext_vector_type(4))) float f32x4;
typedef unsigned short u16;
typedef unsigned int u32;

#define CL 16              // chunk length (timesteps per handoff)
#define NCHUNK 24          // 384 / CL
#define RING 4             // ring depth per (layer,stream)
#define CHSZ (16*CL*128)   // u16 per chunk slot = 32768

__device__ __forceinline__ u16 f2bf(float f){
  u32 x = __float_as_uint(f);
  u32 r = x + 0x7fffu + ((x >> 16) & 1u);
  return (u16)(r >> 16);
}
__device__ __forceinline__ float bf2f(u16 u){
  return __uint_as_float(((u32)u) << 16);
}
__device__ __forceinline__ f32x4 mfma16(short8 a, short8 b, f32x4 c){
  return __builtin_amdgcn_mfma_f32_16x16x32_bf16(a, b, c, 0, 0, 0);
}

// ---------------- merged prologue: init + conv-weight prep + GRU-weight prep ----------------
// bid < 179          : zero S/ssq/Flg(incl convF)/Mx/Macc
// 179 <= bid < 1203  : conv weights [k][f][c] bf16 + W1 transpose
// 1203 <= bid < 1971 : GRU weight transpose (LDS-tiled)
__global__ __launch_bounds__(256) void k_pro(
    float* S, float* ssq, u32* Flg, float* Mx, float* Macc,
    const float* __restrict__ wr, const float* __restrict__ wi,
    const float* __restrict__ w1,
    u16* WtR, u16* WtI, u16* WtIN, u16* W1t,
    const float* __restrict__ g0_kr, const float* __restrict__ g0_ki,
    const float* __restrict__ gs_kr, const float* __restrict__ gs_ki,
    const float* __restrict__ g0_rkr, const float* __restrict__ g0_rki,
    const float* __restrict__ gs_rkr, const float* __restrict__ gs_rki,
    u16* __restrict__ KT, u16* __restrict__ RKT){
  __shared__ float tile[128][33];
  int bid = blockIdx.x, tid = threadIdx.x;
  if (bid < 179){
    int i = bid*256 + tid;
    if (i < 32768){ S[i] = 0.f; return; }
    i -= 32768;
    if (i < 16){ ssq[i] = 0.f; return; }
    i -= 16;
    if (i < 4608){ Flg[i] = 0u; return; }   // prod/cons + convF
    i -= 4608;
    if (i < 4096){ Mx[i] = 0.f; return; }
    i -= 4096;
    if (i < 4096){ Macc[i] = 0.f; return; }
    return;
  }
  if (bid < 1203){
    int i = (bid - 179)*256 + tid;
    if (i < 131072){
      int k = i >> 12, r = i & 4095, f = r >> 6, c = r & 63;
      float a = wr[(k<<12) + (c<<6) + f];
      float b = wi[(k<<12) + (c<<6) + f];
      WtR[i] = f2bf(a); WtI[i] = f2bf(b); WtIN[i] = f2bf(-b);
    } else {
      int j = i - 131072;           // j = col*128 + k ;  W1t[col][k] = w1[k][col]
      int col = j >> 7, k = j & 127;
      W1t[j] = f2bf(w1[(k<<10) + col]);
    }
    return;
  }
  {
    int bid2 = bid - 1203;
    int ct = bid2 % 12; int lm = (bid2/12) & 31; int which = bid2 / (12*32);
    int m = lm & 1, l = lm >> 1;
    int c0 = ct*32;
    for (int idx = tid; idx < 128*32; idx += 256){
      int k = idx >> 5, cc = idx & 31;
      float v;
      if (!which){
        if (l == 0) v = (k < 64) ? (m ? g0_ki : g0_kr)[k*384 + c0+cc] : 0.f;
        else        v = (m ? gs_ki : gs_kr)[((size_t)(l-1)*128 + k)*384 + c0+cc];
      } else {
        if (l == 0) v = (m ? g0_rki : g0_rkr)[k*384 + c0+cc];
        else        v = (m ? gs_rki : gs_rkr)[((size_t)(l-1)*128 + k)*384 + c0+cc];
      }
      tile[k][cc] = v;
    }
    __syncthreads();
    u16* dst = (which ? RKT : KT) + (size_t)lm*384*128;
    for (int idx = tid; idx < 32*128; idx += 256){
      int cc = idx >> 7, k = idx & 127;
      dst[(size_t)(c0+cc)*128 + k] = f2bf(tile[k][cc]);
    }
  }
}

// ---------------- merged persistent kernel: GRU scan (bid<64) + conv1d (bid>=64) ----------------
// Scan: R7 protocol, byte-identical compute (CL=16, RING=4, x-proj hoist).
// Conv blocks (192): 32-wide t-tile (b = cb&15, w = cb>>4), publish per-window
// counters convF[w] (one-shot release; 16 tiles/window). Scan l==0 blocks gate
// chunk-c staging on convF[c>>1]==16 + acquire fence. Conv work is absorbed by
// the CUs that sit idle during the scan's pipeline fill.
__global__ __launch_bounds__(512,1) void k_scanp(
    u16* __restrict__ X0, const u16* __restrict__ KT, const u16* __restrict__ RKT,
    const float* __restrict__ g0_br, const float* __restrict__ g0_bi,
    const float* __restrict__ gs_br, const float* __restrict__ gs_bi,
    u16* __restrict__ HC, u16* __restrict__ HS15, u32* Flg,
    const float* __restrict__ hr, const float* __restrict__ hi,
    const u16* __restrict__ WtR, const u16* __restrict__ WtI, const u16* __restrict__ WtIN,
    const float* __restrict__ gr, const float* __restrict__ gi,
    const float* __restrict__ vr, const float* __restrict__ vi,
    const float* __restrict__ br, const float* __restrict__ bi,
    const float* __restrict__ mr, const float* __restrict__ mi)
{
  __shared__ __align__(16) char smem[75776];
  int bid = blockIdx.x;
  int tid = threadIdx.x, lane = tid & 63, wv = tid >> 6, lr = lane & 15, lg = lane >> 4;
  u32* convF = Flg + 4096;   // convF[w] at convF[w*32]

  if (bid >= 64){
    // ================= conv path =================
    u16* xst = (u16*)smem;            // [part][row 0..62][c], 16384 B
    int cb = bid - 64;                // 0..191
    int w = cb >> 4, b = cb & 15;
    int t0 = w * 32;
    for (int el = tid; el < 2*63*64; el += 512){
      int part = el / (63*64); int rem = el % (63*64); int row = rem >> 6; int c = rem & 63;
      int tg = t0 + row - 15;
      const float* src = part ? hi : hr;
      float v = (tg >= 0 && tg < 384) ? src[((size_t)b*384 + tg)*64 + c] : 0.f;
      int idx = (part*64 + row)*64 + c;
      int byte = (idx<<1) ^ ((row&7)<<4);
      *(u16*)((char*)xst + byte) = f2bf(v);
    }
    __syncthreads();
    if (wv < 4){
      int wid = wv;
      f32x4 accr = {0,0,0,0}, acci = {0,0,0,0};
      f32x4 accr2 = {0,0,0,0}, acci2 = {0,0,0,0};
      for (int k = 0; k < 32; ++k){
        int row = lr + k;
        int row2 = row + 16;
        int swz = (row&7)<<4, swz2 = (row2&7)<<4;
        for (int ch = 0; ch < 2; ++ch){
          int c0 = ch*32 + lg*8;
          int idxr  = (0*64 + row )*64 + c0;
          int idxi  = (1*64 + row )*64 + c0;
          int idxr2 = (0*64 + row2)*64 + c0;
          int idxi2 = (1*64 + row2)*64 + c0;
          short8 ar  = *(const short8*)((const char*)xst + ((idxr <<1) ^ swz));
          short8 ai  = *(const short8*)((const char*)xst + ((idxi <<1) ^ swz));
          short8 ar2 = *(const short8*)((const char*)xst + ((idxr2<<1) ^ swz2));
          short8 ai2 = *(const short8*)((const char*)xst + ((idxi2<<1) ^ swz2));
          size_t wb = ((size_t)(k*64 + wid*16 + lr))*64 + c0;
          short8 bwr = *(const short8*)(WtR + wb);
          short8 bwi = *(const short8*)(WtI + wb);
          short8 bwn = *(const short8*)(WtIN + wb);
          accr  = mfma16(ar,  bwr, accr);
          accr  = mfma16(ai,  bwn, accr);
          acci  = mfma16(ai,  bwr, acci);
          acci  = mfma16(ar,  bwi, acci);
          accr2 = mfma16(ar2, bwr, accr2);
          accr2 = mfma16(ai2, bwn, accr2);
          acci2 = mfma16(ai2, bwr, acci2);
          acci2 = mfma16(ar2, bwi, acci2);
        }
      }
      int f = wid*16 + lr;
      float sr_ = gr[f] * rsqrtf(vr[f] + 1e-3f), or_ = br[f] - mr[f]*sr_;
      float si_ = gi[f] * rsqrtf(vi[f] + 1e-3f), oi_ = bi[f] - mi[f]*si_;
      for (int r = 0; r < 4; ++r){
        int t  = t0 + lg*4 + r;
        int t2 = t0 + 16 + lg*4 + r;
        X0[(((size_t)0*16 + b)*384 + t )*64 + f] = f2bf(accr[r] *sr_ + or_);
        X0[(((size_t)1*16 + b)*384 + t )*64 + f] = f2bf(acci[r] *si_ + oi_);
        X0[(((size_t)0*16 + b)*384 + t2)*64 + f] = f2bf(accr2[r]*sr_ + or_);
        X0[(((size_t)1*16 + b)*384 + t2)*64 + f] = f2bf(acci2[r]*si_ + oi_);
      }
    }
    __syncthreads();   // all waves' X0 stores drained (vmcnt 0) before publish
    if (tid == 0){
      __hip_atomic_fetch_add(&convF[w*32], 1u, __ATOMIC_RELEASE, __HIP_MEMORY_SCOPE_AGENT);
    }
    return;
  }

  // ================= scan path (R15-green, plus convF gate on l==0) =================
  int l = bid >> 2, s = bid & 3;
  u16* xs  = (u16*)smem;                       // 64KB staged x chunk (swizzled)
  u16* hs2 = (u16*)(smem + 65536);             // 8KB double-buffered h
  float (*bsh)[128] = (float(*)[128])(smem + 65536 + 8192);  // folded biases

  int m = s >> 1;

  const float* Bsrc = (l == 0) ? (m ? g0_bi : g0_br)
                               : ((m ? gs_bi : gs_br) + (size_t)(l-1)*768);
  if (tid < 128){
    int j = tid;
    bsh[0][j] = Bsrc[j]       + Bsrc[384 + j];
    bsh[1][j] = Bsrc[128 + j] + Bsrc[384 + 128 + j];
    bsh[2][j] = Bsrc[256 + j];
    bsh[3][j] = Bsrc[384 + 256 + j];
  }
  for (int i = tid; i < 2048; i += 512) ((u32*)hs2)[i] = 0u;

  const u16* Kp  = KT  + (size_t)(l*2 + m)*384*128;
  const u16* RKp = RKT + (size_t)(l*2 + m)*384*128;
  int cz = wv*16 + lr;
  short8 wz[8], wr2[8], whx[4], whr[4];
  #pragma unroll
  for (int ks = 0; ks < 4; ++ks){
    wz[ks]    = *(const short8*)(RKp + (size_t)cz*128 + ks*32 + lg*8);
    wz[4+ks]  = *(const short8*)(Kp  + (size_t)cz*128 + ks*32 + lg*8);
    wr2[ks]   = *(const short8*)(RKp + (size_t)(128+cz)*128 + ks*32 + lg*8);
    wr2[4+ks] = *(const short8*)(Kp  + (size_t)(128+cz)*128 + ks*32 + lg*8);
    whx[ks]   = *(const short8*)(Kp  + (size_t)(256+cz)*128 + ks*32 + lg*8);
    whr[ks]   = *(const short8*)(RKp + (size_t)(256+cz)*128 + ks*32 + lg*8);
  }

  float hreg[4] = {0.f, 0.f, 0.f, 0.f};

  __syncthreads();
  float bz, br_, bhx, bhr;
  {
    int j = wv*16 + lr;
    bz = bsh[0][j]; br_ = bsh[1][j]; bhx = bsh[2][j]; bhr = bsh[3][j];
  }

  u32* prodF = Flg;              // prod[i] at Flg[i*32]
  u32* consF = Flg + 2048;       // cons[i] at Flg[2048+i*32]
  int sA = (s & 1) ? 1 : 0, sB = (s & 1) ? 2 : 3;
  int pA = (l-1)*4 + sA, pB = (l-1)*4 + sB;
  float sgn = (s & 1) ? 1.f : -1.f;
  int p = s & 1;
  int me = l*4 + s;

  for (int c = 0; c < NCHUNK; ++c){
    int t0 = c * CL;
    int slot = c & (RING-1);

    if (tid == 0){
      int guard = 0;
      if (l > 0){
        while (__hip_atomic_load(&prodF[pA*32], __ATOMIC_RELAXED, __HIP_MEMORY_SCOPE_AGENT) < (u32)(c+1) ||
               __hip_atomic_load(&prodF[pB*32], __ATOMIC_RELAXED, __HIP_MEMORY_SCOPE_AGENT) < (u32)(c+1)){
          __builtin_amdgcn_s_sleep(1);
          if (++guard > 10000000) break;
        }
      } else {
        while (__hip_atomic_load(&convF[(c>>1)*32], __ATOMIC_RELAXED, __HIP_MEMORY_SCOPE_AGENT) < 16u){
          __builtin_amdgcn_s_sleep(1);
          if (++guard > 10000000) break;
        }
      }
      if (l < 15 && c >= RING){
        guard = 0;
        while (__hip_atomic_load(&consF[me*32], __ATOMIC_RELAXED, __HIP_MEMORY_SCOPE_AGENT) < (u32)(2*(c-RING+1))){
          __builtin_amdgcn_s_sleep(1);
          if (++guard > 10000000) break;
        }
      }
    }
    __syncthreads();

    if (l == 0){
      __builtin_amdgcn_fence(__ATOMIC_ACQUIRE, "agent");   // pair with conv release
      short8 v[8];
      #pragma unroll
      for (int it = 0; it < 8; ++it){
        int g = tid + it*512;
        int k8 = g & 15, ttv = (g>>4) & 15, b = g >> 8;
        short8 t = {0,0,0,0,0,0,0,0};
        if (k8 < 8) t = *(const short8*)(X0 + (((size_t)p*16 + b)*384 + t0 + ttv)*64 + k8*8);
        v[it] = t;
      }
      asm volatile("" ::: "memory");
      #pragma unroll
      for (int it = 0; it < 8; ++it){
        int g = tid + it*512;
        int k8 = g & 15, ttv = (g>>4) & 15, b = g >> 8;
        int byte = (((b*CL + ttv)*128 + k8*8) << 1) ^ ((b&7)<<4);
        *(short8*)((char*)xs + byte) = v[it];
      }
      __syncthreads();
    } else {
      __builtin_amdgcn_fence(__ATOMIC_ACQUIRE, "agent");
      const u16* baseA = HC + ((size_t)pA*RING + slot)*CHSZ;
      const u16* baseB = HC + ((size_t)pB*RING + slot)*CHSZ;
      short8 va[8], vb[8];
      #pragma unroll
      for (int it = 0; it < 8; ++it){
        int g = tid + it*512;
        int k8 = g & 15, ttv = (g>>4) & 15, b = g >> 8;
        size_t si = ((size_t)b*CL + ttv)*128 + k8*8;
        va[it] = *(const short8*)(baseA + si);
        vb[it] = *(const short8*)(baseB + si);
      }
      asm volatile("" ::: "memory");
      #pragma unroll
      for (int it = 0; it < 8; ++it){
        int g = tid + it*512;
        int k8 = g & 15, ttv = (g>>4) & 15, b = g >> 8;
        short8 o;
        #pragma unroll
        for (int e = 0; e < 8; ++e){
          float f = bf2f((u16)va[it][e]) + sgn*bf2f((u16)vb[it][e]);
          o[e] = (short)f2bf(f);
        }
        int byte = (((b*CL + ttv)*128 + k8*8) << 1) ^ ((b&7)<<4);
        *(short8*)((char*)xs + byte) = o;
      }
      __syncthreads();
      if (tid == 0){
        __hip_atomic_fetch_add(&consF[pA*32], 1u, __ATOMIC_RELAXED, __HIP_MEMORY_SCOPE_AGENT);
        __hip_atomic_fetch_add(&consF[pB*32], 1u, __ATOMIC_RELAXED, __HIP_MEMORY_SCOPE_AGENT);
      }
    }

    u16* outp;
    int Tp, tbase;
    if (l < 15){
      outp = HC + ((size_t)me*RING + slot)*CHSZ;
      Tp = CL; tbase = 0;
    } else {
      outp = HS15 + (size_t)s*16*384*128;
      Tp = 384; tbase = t0;
    }

    for (int q = 0; q < 4; ++q){
      f32x4 xpz[4], xpr[4], xph[4];
      #pragma unroll
      for (int t2 = 0; t2 < 4; ++t2){
        int tt = q*4 + t2;
        short8 ax[4];
        #pragma unroll
        for (int ks = 0; ks < 4; ++ks){
          int xb = (((lr*CL + tt)*128 + ks*32 + lg*8) << 1) ^ ((lr&7)<<4);
          ax[ks] = *(const short8*)((char*)xs + xb);
        }
        f32x4 az  = {bz, bz, bz, bz};
        f32x4 ar  = {br_, br_, br_, br_};
        f32x4 ahx = {bhx, bhx, bhx, bhx};
        #pragma unroll
        for (int ks = 0; ks < 4; ++ks){
          az  = mfma16(ax[ks], wz[4+ks],  az);
          ar  = mfma16(ax[ks], wr2[4+ks], ar);
          ahx = mfma16(ax[ks], whx[ks],   ahx);
        }
        xpz[t2] = az; xpr[t2] = ar; xph[t2] = ahx;
      }
      #pragma unroll
      for (int t2 = 0; t2 < 4; ++t2){
        int tt = q*4 + t2;
        int hp = tt & 1;
        short8 ah[4];
        #pragma unroll
        for (int ks = 0; ks < 4; ++ks){
          int hb = hp*4096 + (((lr*128 + ks*32 + lg*8) << 1) ^ ((lr&7)<<4));
          ah[ks] = *(const short8*)((char*)hs2 + hb);
        }
        f32x4 az  = xpz[t2];
        f32x4 ar  = xpr[t2];
        f32x4 ahr = {bhr, bhr, bhr, bhr};
        #pragma unroll
        for (int ks = 0; ks < 4; ++ks){
          az  = mfma16(ah[ks], wz[ks],  az);
          ar  = mfma16(ah[ks], wr2[ks], ar);
          ahr = mfma16(ah[ks], whr[ks], ahr);
        }
        int j = wv*16 + lr;
        #pragma unroll
        for (int r = 0; r < 4; ++r){
          int b = lg*4 + r;
          float z  = 1.f/(1.f + __expf(-az[r]));
          float rg = 1.f/(1.f + __expf(-ar[r]));
          float pre = xph[t2][r] + rg*ahr[r];
          pre = fminf(fmaxf(pre, -15.f), 15.f);
          float e2 = __expf(2.f*pre);
          float hh = (e2 - 1.f)/(e2 + 1.f);
          float hn = z*hreg[r] + (1.f - z)*hh;
          hreg[r] = hn;
          u16 hb16 = f2bf(hn);
          int byte = ((hp^1)*4096) + ((((b*128 + j) << 1)) ^ ((b&7)<<4));
          *(u16*)((char*)hs2 + byte) = hb16;
          outp[((size_t)b*Tp + tbase + tt)*128 + j] = hb16;
        }
        __syncthreads();
      }
    }

    if (l < 15 && tid == 0){
      __hip_atomic_fetch_add(&prodF[me*32], 1u, __ATOMIC_RELEASE, __HIP_MEMORY_SCOPE_AGENT);
    }
  }
}

// ---------------- FF hidden pass + fused mean-pool partials ----------------
__global__ __launch_bounds__(256) void k_ffs(const u16* __restrict__ HS, const u16* __restrict__ W1t,
                                             const float* __restrict__ b1, float* __restrict__ S,
                                             float* __restrict__ Mx){
  int bid = blockIdx.x;
  int part = bid / 384; int rem = bid % 384;
  int b = rem / 24; int rem2 = rem % 24;
  int t0 = (rem2 / 4) * 64, c0 = (rem2 % 4) * 256;
  int tid = threadIdx.x, lane = tid & 63, wid = tid >> 6, lr = lane & 15, lg = lane >> 4;
  int sA = part ? 1 : 0, sB = part ? 2 : 3;
  float sgn = part ? 1.f : -1.f;
  short8 af[4][4];
  #pragma unroll
  for (int rt = 0; rt < 4; ++rt)
    #pragma unroll
    for (int ks = 0; ks < 4; ++ks){
      size_t i1 = (((size_t)sA*16 + b)*384 + t0 + rt*16 + lr)*128 + ks*32 + lg*8;
      size_t i2 = (((size_t)sB*16 + b)*384 + t0 + rt*16 + lr)*128 + ks*32 + lg*8;
      short8 va = *(const short8*)(HS + i1);
      short8 vb = *(const short8*)(HS + i2);
      short8 o;
      #pragma unroll
      for (int e = 0; e < 8; ++e){
        float f = bf2f((u16)va[e]) + sgn*bf2f((u16)vb[e]);
        o[e] = (short)f2bf(f);
      }
      af[rt][ks] = o;
    }
  if (rem2 % 4 == 0 && wid == 0){
    #pragma unroll
    for (int ks = 0; ks < 4; ++ks){
      #pragma unroll
      for (int e = 0; e < 8; ++e){
        float s = 0.f;
        #pragma unroll
        for (int rt = 0; rt < 4; ++rt) s += bf2f((u16)af[rt][ks][e]);
        s += __shfl_xor(s, 1, 64);
        s += __shfl_xor(s, 2, 64);
        s += __shfl_xor(s, 4, 64);
        s += __shfl_xor(s, 8, 64);
        if (lr == 0) atomicAdd(&Mx[((size_t)part*16 + b)*128 + ks*32 + lg*8 + e], s);
      }
    }
  }
  for (int ctl = 0; ctl < 4; ++ctl){
    int col = c0 + wid*64 + ctl*16 + lr;
    short8 bf[4];
    #pragma unroll
    for (int ks = 0; ks < 4; ++ks)
      bf[ks] = *(const short8*)(W1t + (size_t)col*128 + ks*32 + lg*8);
    float bias = b1[col];
    float ssum = 0.f;
    #pragma unroll
    for (int rt = 0; rt < 4; ++rt){
      f32x4 acc = {0,0,0,0};
      #pragma unroll
      for (int ks = 0; ks < 4; ++ks) acc = mfma16(af[rt][ks], bf[ks], acc);
      #pragma unroll
      for (int r = 0; r < 4; ++r) ssum += fmaxf(acc[r] + bias, 0.f);
    }
    ssum += __shfl_xor(ssum, 16, 64);
    ssum += __shfl_xor(ssum, 32, 64);
    if (lg == 0) atomicAdd(&S[((size_t)part*16 + b)*1024 + col], ssum);
  }
}

// ---------------- combine partials: Macc[pb][u] += sum_{f in quarter} S[f]*w2[f][u] ----------------
__global__ void k_combp(const float* __restrict__ S, const float* __restrict__ w2,
                        float* __restrict__ Macc){
  int bid = blockIdx.x; int u = threadIdx.x;
  int pb = bid >> 2, fq = bid & 3;
  const float* Sp = S + (size_t)pb*1024;
  float acc = 0.f;
  for (int f = fq*256; f < fq*256 + 256; ++f) acc += Sp[f] * w2[(size_t)f*128 + u];
  atomicAdd(&Macc[pb*128 + u], acc);
}

// ---------------- Q/R heads (f32) + sum|Q|^2 (folds M = (Mx+Macc)/384 + b2) ----------------
__global__ __launch_bounds__(256) void k_qr(const float* __restrict__ Mx,
    const float* __restrict__ Macc, const float* __restrict__ b2,
    const float* __restrict__ qr_w, const float* __restrict__ qr_b,
    const float* __restrict__ qi_w, const float* __restrict__ qi_b,
    const float* __restrict__ rr_w, const float* __restrict__ rr_b,
    const float* __restrict__ ri_w, const float* __restrict__ ri_b,
    float* __restrict__ out, float* __restrict__ ssq){
  __shared__ float smr[128], smi[128];
  int bid = blockIdx.x; int tid = threadIdx.x;
  int b = bid >> 4; int o = (bid & 15)*256 + tid;
  if (tid < 128){
    smr[tid] = (Mx[b*128 + tid]        + Macc[b*128 + tid]       ) * (1.f/384.f) + b2[tid];
    smi[tid] = (Mx[(16 + b)*128 + tid] + Macc[(16 + b)*128 + tid]) * (1.f/384.f) + b2[tid];
  }
  __syncthreads();
  float aq=0, bq=0, cq=0, dq=0, ar=0, br2=0, cr=0, dr=0;
  for (int u = 0; u < 128; ++u){
    float mr = smr[u], mi = smi[u];
    float wqr = qr_w[(size_t)u*4096 + o], wqi = qi_w[(size_t)u*4096 + o];
    float wrr = rr_w[(size_t)u*4096 + o], wri = ri_w[(size_t)u*4096 + o];
    aq += mr*wqr;  bq += mi*wqi;  cq += mi*wqr;  dq += mr*wqi;
    ar += mr*wrr;  br2 += mi*wri; cr += mi*wrr;  dr += mr*wri;
  }
  float Qr = (aq + qr_b[o]) - (bq + qi_b[o]);
  float Qi = (cq + qr_b[o]) + (dq + qi_b[o]);
  float Rr = (ar + rr_b[o]) - (br2 + ri_b[o]);
  float Ri = (cr + rr_b[o]) + (dr + ri_b[o]);
  out[(size_t)b*4096 + o] = Qr;
  out[65536 + (size_t)b*4096 + o] = Qi;
  out[131072 + (size_t)b*4096 + o] = Rr;
  out[196608 + (size_t)b*4096 + o] = Ri;
  float ss = Qr*Qr + Qi*Qi;
  for (int off = 32; off; off >>= 1) ss += __shfl_down(ss, off, 64);
  if ((tid & 63) == 0) atomicAdd(&ssq[b], ss);
}

// ---------------- scale Q by sqrt(N)/nrm ----------------
__global__ void k_scale(float* __restrict__ out, const float* __restrict__ ssq){
  int i = blockIdx.x*256 + threadIdx.x;   // covers Qr and Qi regions: 131072
  int b = (i >> 12) & 15;
  float s = 8.f / sqrtf(ssq[b]);
  out[i] *= s;
}

extern "C" void kernel_launch(void* const* d_in, const int* in_sizes, int n_in,
                              void* d_out, int out_size, void* d_ws, size_t ws_size,
                              hipStream_t stream){
  const float* h_real = (const float*)d_in[0];
  const float* h_imag = (const float*)d_in[1];
  const float* conv_wr = (const float*)d_in[2];
  const float* conv_wi = (const float*)d_in[3];
  const float* bn_gr = (const float*)d_in[4];
  const float* bn_gi = (const float*)d_in[5];
  const float* bn_vr = (const float*)d_in[6];
  const float* bn_vi = (const float*)d_in[7];
  const float* bn_br = (const float*)d_in[8];
  const float* bn_bi = (const float*)d_in[9];
  const float* bn_mr = (const float*)d_in[10];
  const float* bn_mi = (const float*)d_in[11];
  const float* g0_kr = (const float*)d_in[12];
  const float* g0_rkr = (const float*)d_in[13];
  const float* g0_br = (const float*)d_in[14];
  const float* g0_ki = (const float*)d_in[15];
  const float* g0_rki = (const float*)d_in[16];
  const float* g0_bi = (const float*)d_in[17];
  const float* gs_kr = (const float*)d_in[18];
  const float* gs_rkr = (const float*)d_in[19];
  const float* gs_br = (const float*)d_in[20];
  const float* gs_ki = (const float*)d_in[21];
  const float* gs_rki = (const float*)d_in[22];
  const float* gs_bi = (const float*)d_in[23];
  const float* ff1_w = (const float*)d_in[24];
  const float* ff1_b = (const float*)d_in[25];
  const float* ff2_w = (const float*)d_in[26];
  const float* ff2_b = (const float*)d_in[27];
  const float* qr_w = (const float*)d_in[28];
  const float* qr_b = (const float*)d_in[29];
  const float* qi_w = (const float*)d_in[30];
  const float* qi_b = (const float*)d_in[31];
  const float* rr_w = (const float*)d_in[32];
  const float* rr_b = (const float*)d_in[33];
  const float* ri_w = (const float*)d_in[34];
  const float* ri_b = (const float*)d_in[35];

  char* ws = (char*)d_ws; size_t off = 0;
  auto carve = [&](size_t bytes)->char*{ char* p = ws + off; off += (bytes + 255) & ~(size_t)255; return p; };
  u16* X0   = (u16*)carve((size_t)2*16*384*64*2);          // 1.5 MB
  u16* HC   = (u16*)carve((size_t)64*RING*CHSZ*2);         // 16.8 MB chunk ring
  u16* HS15 = (u16*)carve((size_t)4*16*384*128*2);         // 6.3 MB (layer-15 full-seq streams)
  u16* KT   = (u16*)carve((size_t)16*2*384*128*2);         // 3.1 MB
  u16* RKT  = (u16*)carve((size_t)16*2*384*128*2);         // 3.1 MB
  u16* WtR  = (u16*)carve(131072*2);
  u16* WtI  = (u16*)carve(131072*2);
  u16* WtIN = (u16*)carve(131072*2);
  u16* W1t  = (u16*)carve(131072*2);
  u32* Flg  = (u32*)carve(4608*4);                         // prod/cons/conv flags (128B padded)
  float* S  = (float*)carve(32768*4);
  float* Mx = (float*)carve(4096*4);
  float* Macc = (float*)carve(4096*4);
  float* ssq = (float*)carve(256);

  k_pro<<<1971, 256, 0, stream>>>(S, ssq, Flg, Mx, Macc,
                                  conv_wr, conv_wi, ff1_w, WtR, WtI, WtIN, W1t,
                                  g0_kr, g0_ki, gs_kr, gs_ki,
                                  g0_rkr, g0_rki, gs_rkr, gs_rki, KT, RKT);
  k_scanp<<<256, 512, 0, stream>>>(X0, KT, RKT, g0_br, g0_bi, gs_br, gs_bi,
                                   HC, HS15, Flg,
                                   h_real, h_imag, WtR, WtI, WtIN,
                                   bn_gr, bn_gi, bn_vr, bn_vi, bn_br, bn_bi, bn_mr, bn_mi);
  k_ffs<<<768, 256, 0, stream>>>(HS15, W1t, ff1_b, S, Mx);
  k_combp<<<128, 128, 0, stream>>>(S, ff2_w, Macc);
  k_qr<<<256, 256, 0, stream>>>(Mx, Macc, ff2_b, qr_w, qr_b, qi_w, qi_b,
                                rr_w, rr_b, ri_w, ri_b, (float*)d_out, ssq);
  k_scale<<<512, 256, 0, stream>>>((float*)d_out, ssq);
}

// Round 17
// 1046.257 us; speedup vs baseline: 1.0451x; 1.0136x over previous
//
#include <hip/hip_runtime.h>
#include <hip/hip_bf16.h>
#include <math.h>

typedef __attribute__((ext_vector_type(8))) short short8;
typedef __attribute__((ext_vector_type(4))) float f32x4;
typedef unsigned short u16;
typedef unsigned int u32;

#define CL 16              // chunk length (timesteps per handoff)
#define NCHUNK 24          // 384 / CL
#define RING 4             // ring depth per (layer,stream)
#define CHSZ (16*CL*128)   // u16 per chunk slot = 32768

__device__ __forceinline__ u16 f2bf(float f){
  u32 x = __float_as_uint(f);
  u32 r = x + 0x7fffu + ((x >> 16) & 1u);
  return (u16)(r >> 16);
}
__device__ __forceinline__ float bf2f(u16 u){
  return __uint_as_float(((u32)u) << 16);
}
__device__ __forceinline__ f32x4 mfma16(short8 a, short8 b, f32x4 c){
  return __builtin_amdgcn_mfma_f32_16x16x32_bf16(a, b, c, 0, 0, 0);
}

// ---------------- merged prologue: init + conv-weight prep + GRU-weight prep ----------------
// bid < 179          : zero S/ssq/Flg(incl convF)/Mx/Macc
// 179 <= bid < 1203  : conv weights [k][f][c] bf16 (WtR/WtI) + W1 transpose
// 1203 <= bid < 1971 : GRU weight transpose (LDS-tiled)
__global__ __launch_bounds__(256) void k_pro(
    float* S, float* ssq, u32* Flg, float* Mx, float* Macc,
    const float* __restrict__ wr, const float* __restrict__ wi,
    const float* __restrict__ w1,
    u16* WtR, u16* WtI, u16* W1t,
    const float* __restrict__ g0_kr, const float* __restrict__ g0_ki,
    const float* __restrict__ gs_kr, const float* __restrict__ gs_ki,
    const float* __restrict__ g0_rkr, const float* __restrict__ g0_rki,
    const float* __restrict__ gs_rkr, const float* __restrict__ gs_rki,
    u16* __restrict__ KT, u16* __restrict__ RKT){
  __shared__ float tile[128][33];
  int bid = blockIdx.x, tid = threadIdx.x;
  if (bid < 179){
    int i = bid*256 + tid;
    if (i < 32768){ S[i] = 0.f; return; }
    i -= 32768;
    if (i < 16){ ssq[i] = 0.f; return; }
    i -= 16;
    if (i < 4608){ Flg[i] = 0u; return; }   // prod/cons + convF
    i -= 4608;
    if (i < 4096){ Mx[i] = 0.f; return; }
    i -= 4096;
    if (i < 4096){ Macc[i] = 0.f; return; }
    return;
  }
  if (bid < 1203){
    int i = (bid - 179)*256 + tid;
    if (i < 131072){
      int k = i >> 12, r = i & 4095, f = r >> 6, c = r & 63;
      float a = wr[(k<<12) + (c<<6) + f];
      float b = wi[(k<<12) + (c<<6) + f];
      WtR[i] = f2bf(a); WtI[i] = f2bf(b);
    } else {
      int j = i - 131072;           // j = col*128 + k ;  W1t[col][k] = w1[k][col]
      int col = j >> 7, k = j & 127;
      W1t[j] = f2bf(w1[(k<<10) + col]);
    }
    return;
  }
  {
    int bid2 = bid - 1203;
    int ct = bid2 % 12; int lm = (bid2/12) & 31; int which = bid2 / (12*32);
    int m = lm & 1, l = lm >> 1;
    int c0 = ct*32;
    for (int idx = tid; idx < 128*32; idx += 256){
      int k = idx >> 5, cc = idx & 31;
      float v;
      if (!which){
        if (l == 0) v = (k < 64) ? (m ? g0_ki : g0_kr)[k*384 + c0+cc] : 0.f;
        else        v = (m ? gs_ki : gs_kr)[((size_t)(l-1)*128 + k)*384 + c0+cc];
      } else {
        if (l == 0) v = (m ? g0_rki : g0_rkr)[k*384 + c0+cc];
        else        v = (m ? gs_rki : gs_rkr)[((size_t)(l-1)*128 + k)*384 + c0+cc];
      }
      tile[k][cc] = v;
    }
    __syncthreads();
    u16* dst = (which ? RKT : KT) + (size_t)lm*384*128;
    for (int idx = tid; idx < 32*128; idx += 256){
      int cc = idx >> 7, k = idx & 127;
      dst[(size_t)(c0+cc)*128 + k] = f2bf(tile[k][cc]);
    }
  }
}

// ---------------- merged persistent kernel: GRU scan (bid<64) + conv1d (bid>=64) ----------------
// Scan: R7 protocol, byte-identical compute (CL=16, RING=4, x-proj hoist).
// Conv blocks (192): 32-wide t-tile, two-accumulator real part (accr = P - N,
// no WtIN array: weight traffic per tile 786->524 KB -> window 0 publishes
// sooner, shortening the scan's gated entry). Publish convF[w] one-shot
// release; scan l==0 gates chunk c on convF[c>>1]==16 + acquire fence.
__global__ __launch_bounds__(512,1) void k_scanp(
    u16* __restrict__ X0, const u16* __restrict__ KT, const u16* __restrict__ RKT,
    const float* __restrict__ g0_br, const float* __restrict__ g0_bi,
    const float* __restrict__ gs_br, const float* __restrict__ gs_bi,
    u16* __restrict__ HC, u16* __restrict__ HS15, u32* Flg,
    const float* __restrict__ hr, const float* __restrict__ hi,
    const u16* __restrict__ WtR, const u16* __restrict__ WtI,
    const float* __restrict__ gr, const float* __restrict__ gi,
    const float* __restrict__ vr, const float* __restrict__ vi,
    const float* __restrict__ br, const float* __restrict__ bi,
    const float* __restrict__ mr, const float* __restrict__ mi)
{
  __shared__ __align__(16) char smem[75776];
  int bid = blockIdx.x;
  int tid = threadIdx.x, lane = tid & 63, wv = tid >> 6, lr = lane & 15, lg = lane >> 4;
  u32* convF = Flg + 4096;   // convF[w] at convF[w*32]

  if (bid >= 64){
    // ================= conv path =================
    u16* xst = (u16*)smem;            // [part][row 0..62][c], 16384 B
    int cb = bid - 64;                // 0..191
    int w = cb >> 4, b = cb & 15;
    int t0 = w * 32;
    for (int el = tid; el < 2*63*64; el += 512){
      int part = el / (63*64); int rem = el % (63*64); int row = rem >> 6; int c = rem & 63;
      int tg = t0 + row - 15;
      const float* src = part ? hi : hr;
      float v = (tg >= 0 && tg < 384) ? src[((size_t)b*384 + tg)*64 + c] : 0.f;
      int idx = (part*64 + row)*64 + c;
      int byte = (idx<<1) ^ ((row&7)<<4);
      *(u16*)((char*)xst + byte) = f2bf(v);
    }
    __syncthreads();
    if (wv < 4){
      int wid = wv;
      f32x4 accrp = {0,0,0,0}, accrn = {0,0,0,0}, acci = {0,0,0,0};
      f32x4 accr2p = {0,0,0,0}, accr2n = {0,0,0,0}, acci2 = {0,0,0,0};
      for (int k = 0; k < 32; ++k){
        int row = lr + k;
        int row2 = row + 16;
        int swz = (row&7)<<4, swz2 = (row2&7)<<4;
        for (int ch = 0; ch < 2; ++ch){
          int c0 = ch*32 + lg*8;
          int idxr  = (0*64 + row )*64 + c0;
          int idxi  = (1*64 + row )*64 + c0;
          int idxr2 = (0*64 + row2)*64 + c0;
          int idxi2 = (1*64 + row2)*64 + c0;
          short8 ar  = *(const short8*)((const char*)xst + ((idxr <<1) ^ swz));
          short8 ai  = *(const short8*)((const char*)xst + ((idxi <<1) ^ swz));
          short8 ar2 = *(const short8*)((const char*)xst + ((idxr2<<1) ^ swz2));
          short8 ai2 = *(const short8*)((const char*)xst + ((idxi2<<1) ^ swz2));
          size_t wb = ((size_t)(k*64 + wid*16 + lr))*64 + c0;
          short8 bwr = *(const short8*)(WtR + wb);
          short8 bwi = *(const short8*)(WtI + wb);
          accrp  = mfma16(ar,  bwr, accrp);
          accrn  = mfma16(ai,  bwi, accrn);
          acci   = mfma16(ai,  bwr, acci);
          acci   = mfma16(ar,  bwi, acci);
          accr2p = mfma16(ar2, bwr, accr2p);
          accr2n = mfma16(ai2, bwi, accr2n);
          acci2  = mfma16(ai2, bwr, acci2);
          acci2  = mfma16(ar2, bwi, acci2);
        }
      }
      int f = wid*16 + lr;
      float sr_ = gr[f] * rsqrtf(vr[f] + 1e-3f), or_ = br[f] - mr[f]*sr_;
      float si_ = gi[f] * rsqrtf(vi[f] + 1e-3f), oi_ = bi[f] - mi[f]*si_;
      for (int r = 0; r < 4; ++r){
        int t  = t0 + lg*4 + r;
        int t2 = t0 + 16 + lg*4 + r;
        X0[(((size_t)0*16 + b)*384 + t )*64 + f] = f2bf((accrp[r] - accrn[r]) *sr_ + or_);
        X0[(((size_t)1*16 + b)*384 + t )*64 + f] = f2bf(acci[r]              *si_ + oi_);
        X0[(((size_t)0*16 + b)*384 + t2)*64 + f] = f2bf((accr2p[r]-accr2n[r])*sr_ + or_);
        X0[(((size_t)1*16 + b)*384 + t2)*64 + f] = f2bf(acci2[r]             *si_ + oi_);
      }
    }
    __syncthreads();   // all waves' X0 stores drained (vmcnt 0) before publish
    if (tid == 0){
      __hip_atomic_fetch_add(&convF[w*32], 1u, __ATOMIC_RELEASE, __HIP_MEMORY_SCOPE_AGENT);
    }
    return;
  }

  // ================= scan path (R16-green, byte-identical) =================
  int l = bid >> 2, s = bid & 3;
  u16* xs  = (u16*)smem;                       // 64KB staged x chunk (swizzled)
  u16* hs2 = (u16*)(smem + 65536);             // 8KB double-buffered h
  float (*bsh)[128] = (float(*)[128])(smem + 65536 + 8192);  // folded biases

  int m = s >> 1;

  const float* Bsrc = (l == 0) ? (m ? g0_bi : g0_br)
                               : ((m ? gs_bi : gs_br) + (size_t)(l-1)*768);
  if (tid < 128){
    int j = tid;
    bsh[0][j] = Bsrc[j]       + Bsrc[384 + j];
    bsh[1][j] = Bsrc[128 + j] + Bsrc[384 + 128 + j];
    bsh[2][j] = Bsrc[256 + j];
    bsh[3][j] = Bsrc[384 + 256 + j];
  }
  for (int i = tid; i < 2048; i += 512) ((u32*)hs2)[i] = 0u;

  const u16* Kp  = KT  + (size_t)(l*2 + m)*384*128;
  const u16* RKp = RKT + (size_t)(l*2 + m)*384*128;
  int cz = wv*16 + lr;
  short8 wz[8], wr2[8], whx[4], whr[4];
  #pragma unroll
  for (int ks = 0; ks < 4; ++ks){
    wz[ks]    = *(const short8*)(RKp + (size_t)cz*128 + ks*32 + lg*8);
    wz[4+ks]  = *(const short8*)(Kp  + (size_t)cz*128 + ks*32 + lg*8);
    wr2[ks]   = *(const short8*)(RKp + (size_t)(128+cz)*128 + ks*32 + lg*8);
    wr2[4+ks] = *(const short8*)(Kp  + (size_t)(128+cz)*128 + ks*32 + lg*8);
    whx[ks]   = *(const short8*)(Kp  + (size_t)(256+cz)*128 + ks*32 + lg*8);
    whr[ks]   = *(const short8*)(RKp + (size_t)(256+cz)*128 + ks*32 + lg*8);
  }

  float hreg[4] = {0.f, 0.f, 0.f, 0.f};

  __syncthreads();
  float bz, br_, bhx, bhr;
  {
    int j = wv*16 + lr;
    bz = bsh[0][j]; br_ = bsh[1][j]; bhx = bsh[2][j]; bhr = bsh[3][j];
  }

  u32* prodF = Flg;              // prod[i] at Flg[i*32]
  u32* consF = Flg + 2048;       // cons[i] at Flg[2048+i*32]
  int sA = (s & 1) ? 1 : 0, sB = (s & 1) ? 2 : 3;
  int pA = (l-1)*4 + sA, pB = (l-1)*4 + sB;
  float sgn = (s & 1) ? 1.f : -1.f;
  int p = s & 1;
  int me = l*4 + s;

  for (int c = 0; c < NCHUNK; ++c){
    int t0 = c * CL;
    int slot = c & (RING-1);

    if (tid == 0){
      int guard = 0;
      if (l > 0){
        while (__hip_atomic_load(&prodF[pA*32], __ATOMIC_RELAXED, __HIP_MEMORY_SCOPE_AGENT) < (u32)(c+1) ||
               __hip_atomic_load(&prodF[pB*32], __ATOMIC_RELAXED, __HIP_MEMORY_SCOPE_AGENT) < (u32)(c+1)){
          __builtin_amdgcn_s_sleep(1);
          if (++guard > 10000000) break;
        }
      } else {
        while (__hip_atomic_load(&convF[(c>>1)*32], __ATOMIC_RELAXED, __HIP_MEMORY_SCOPE_AGENT) < 16u){
          __builtin_amdgcn_s_sleep(1);
          if (++guard > 10000000) break;
        }
      }
      if (l < 15 && c >= RING){
        guard = 0;
        while (__hip_atomic_load(&consF[me*32], __ATOMIC_RELAXED, __HIP_MEMORY_SCOPE_AGENT) < (u32)(2*(c-RING+1))){
          __builtin_amdgcn_s_sleep(1);
          if (++guard > 10000000) break;
        }
      }
    }
    __syncthreads();

    if (l == 0){
      __builtin_amdgcn_fence(__ATOMIC_ACQUIRE, "agent");   // pair with conv release
      short8 v[8];
      #pragma unroll
      for (int it = 0; it < 8; ++it){
        int g = tid + it*512;
        int k8 = g & 15, ttv = (g>>4) & 15, b = g >> 8;
        short8 t = {0,0,0,0,0,0,0,0};
        if (k8 < 8) t = *(const short8*)(X0 + (((size_t)p*16 + b)*384 + t0 + ttv)*64 + k8*8);
        v[it] = t;
      }
      asm volatile("" ::: "memory");
      #pragma unroll
      for (int it = 0; it < 8; ++it){
        int g = tid + it*512;
        int k8 = g & 15, ttv = (g>>4) & 15, b = g >> 8;
        int byte = (((b*CL + ttv)*128 + k8*8) << 1) ^ ((b&7)<<4);
        *(short8*)((char*)xs + byte) = v[it];
      }
      __syncthreads();
    } else {
      __builtin_amdgcn_fence(__ATOMIC_ACQUIRE, "agent");
      const u16* baseA = HC + ((size_t)pA*RING + slot)*CHSZ;
      const u16* baseB = HC + ((size_t)pB*RING + slot)*CHSZ;
      short8 va[8], vb[8];
      #pragma unroll
      for (int it = 0; it < 8; ++it){
        int g = tid + it*512;
        int k8 = g & 15, ttv = (g>>4) & 15, b = g >> 8;
        size_t si = ((size_t)b*CL + ttv)*128 + k8*8;
        va[it] = *(const short8*)(baseA + si);
        vb[it] = *(const short8*)(baseB + si);
      }
      asm volatile("" ::: "memory");
      #pragma unroll
      for (int it = 0; it < 8; ++it){
        int g = tid + it*512;
        int k8 = g & 15, ttv = (g>>4) & 15, b = g >> 8;
        short8 o;
        #pragma unroll
        for (int e = 0; e < 8; ++e){
          float f = bf2f((u16)va[it][e]) + sgn*bf2f((u16)vb[it][e]);
          o[e] = (short)f2bf(f);
        }
        int byte = (((b*CL + ttv)*128 + k8*8) << 1) ^ ((b&7)<<4);
        *(short8*)((char*)xs + byte) = o;
      }
      __syncthreads();
      if (tid == 0){
        __hip_atomic_fetch_add(&consF[pA*32], 1u, __ATOMIC_RELAXED, __HIP_MEMORY_SCOPE_AGENT);
        __hip_atomic_fetch_add(&consF[pB*32], 1u, __ATOMIC_RELAXED, __HIP_MEMORY_SCOPE_AGENT);
      }
    }

    u16* outp;
    int Tp, tbase;
    if (l < 15){
      outp = HC + ((size_t)me*RING + slot)*CHSZ;
      Tp = CL; tbase = 0;
    } else {
      outp = HS15 + (size_t)s*16*384*128;
      Tp = 384; tbase = t0;
    }

    for (int q = 0; q < 4; ++q){
      f32x4 xpz[4], xpr[4], xph[4];
      #pragma unroll
      for (int t2 = 0; t2 < 4; ++t2){
        int tt = q*4 + t2;
        short8 ax[4];
        #pragma unroll
        for (int ks = 0; ks < 4; ++ks){
          int xb = (((lr*CL + tt)*128 + ks*32 + lg*8) << 1) ^ ((lr&7)<<4);
          ax[ks] = *(const short8*)((char*)xs + xb);
        }
        f32x4 az  = {bz, bz, bz, bz};
        f32x4 ar  = {br_, br_, br_, br_};
        f32x4 ahx = {bhx, bhx, bhx, bhx};
        #pragma unroll
        for (int ks = 0; ks < 4; ++ks){
          az  = mfma16(ax[ks], wz[4+ks],  az);
          ar  = mfma16(ax[ks], wr2[4+ks], ar);
          ahx = mfma16(ax[ks], whx[ks],   ahx);
        }
        xpz[t2] = az; xpr[t2] = ar; xph[t2] = ahx;
      }
      #pragma unroll
      for (int t2 = 0; t2 < 4; ++t2){
        int tt = q*4 + t2;
        int hp = tt & 1;
        short8 ah[4];
        #pragma unroll
        for (int ks = 0; ks < 4; ++ks){
          int hb = hp*4096 + (((lr*128 + ks*32 + lg*8) << 1) ^ ((lr&7)<<4));
          ah[ks] = *(const short8*)((char*)hs2 + hb);
        }
        f32x4 az  = xpz[t2];
        f32x4 ar  = xpr[t2];
        f32x4 ahr = {bhr, bhr, bhr, bhr};
        #pragma unroll
        for (int ks = 0; ks < 4; ++ks){
          az  = mfma16(ah[ks], wz[ks],  az);
          ar  = mfma16(ah[ks], wr2[ks], ar);
          ahr = mfma16(ah[ks], whr[ks], ahr);
        }
        int j = wv*16 + lr;
        #pragma unroll
        for (int r = 0; r < 4; ++r){
          int b = lg*4 + r;
          float z  = 1.f/(1.f + __expf(-az[r]));
          float rg = 1.f/(1.f + __expf(-ar[r]));
          float pre = xph[t2][r] + rg*ahr[r];
          pre = fminf(fmaxf(pre, -15.f), 15.f);
          float e2 = __expf(2.f*pre);
          float hh = (e2 - 1.f)/(e2 + 1.f);
          float hn = z*hreg[r] + (1.f - z)*hh;
          hreg[r] = hn;
          u16 hb16 = f2bf(hn);
          int byte = ((hp^1)*4096) + ((((b*128 + j) << 1)) ^ ((b&7)<<4));
          *(u16*)((char*)hs2 + byte) = hb16;
          outp[((size_t)b*Tp + tbase + tt)*128 + j] = hb16;
        }
        __syncthreads();
      }
    }

    if (l < 15 && tid == 0){
      __hip_atomic_fetch_add(&prodF[me*32], 1u, __ATOMIC_RELEASE, __HIP_MEMORY_SCOPE_AGENT);
    }
  }
}

// ---------------- FF hidden pass + fused mean-pool partials ----------------
__global__ __launch_bounds__(256) void k_ffs(const u16* __restrict__ HS, const u16* __restrict__ W1t,
                                             const float* __restrict__ b1, float* __restrict__ S,
                                             float* __restrict__ Mx){
  int bid = blockIdx.x;
  int part = bid / 384; int rem = bid % 384;
  int b = rem / 24; int rem2 = rem % 24;
  int t0 = (rem2 / 4) * 64, c0 = (rem2 % 4) * 256;
  int tid = threadIdx.x, lane = tid & 63, wid = tid >> 6, lr = lane & 15, lg = lane >> 4;
  int sA = part ? 1 : 0, sB = part ? 2 : 3;
  float sgn = part ? 1.f : -1.f;
  short8 af[4][4];
  #pragma unroll
  for (int rt = 0; rt < 4; ++rt)
    #pragma unroll
    for (int ks = 0; ks < 4; ++ks){
      size_t i1 = (((size_t)sA*16 + b)*384 + t0 + rt*16 + lr)*128 + ks*32 + lg*8;
      size_t i2 = (((size_t)sB*16 + b)*384 + t0 + rt*16 + lr)*128 + ks*32 + lg*8;
      short8 va = *(const short8*)(HS + i1);
      short8 vb = *(const short8*)(HS + i2);
      short8 o;
      #pragma unroll
      for (int e = 0; e < 8; ++e){
        float f = bf2f((u16)va[e]) + sgn*bf2f((u16)vb[e]);
        o[e] = (short)f2bf(f);
      }
      af[rt][ks] = o;
    }
  if (rem2 % 4 == 0 && wid == 0){
    #pragma unroll
    for (int ks = 0; ks < 4; ++ks){
      #pragma unroll
      for (int e = 0; e < 8; ++e){
        float s = 0.f;
        #pragma unroll
        for (int rt = 0; rt < 4; ++rt) s += bf2f((u16)af[rt][ks][e]);
        s += __shfl_xor(s, 1, 64);
        s += __shfl_xor(s, 2, 64);
        s += __shfl_xor(s, 4, 64);
        s += __shfl_xor(s, 8, 64);
        if (lr == 0) atomicAdd(&Mx[((size_t)part*16 + b)*128 + ks*32 + lg*8 + e], s);
      }
    }
  }
  for (int ctl = 0; ctl < 4; ++ctl){
    int col = c0 + wid*64 + ctl*16 + lr;
    short8 bf[4];
    #pragma unroll
    for (int ks = 0; ks < 4; ++ks)
      bf[ks] = *(const short8*)(W1t + (size_t)col*128 + ks*32 + lg*8);
    float bias = b1[col];
    float ssum = 0.f;
    #pragma unroll
    for (int rt = 0; rt < 4; ++rt){
      f32x4 acc = {0,0,0,0};
      #pragma unroll
      for (int ks = 0; ks < 4; ++ks) acc = mfma16(af[rt][ks], bf[ks], acc);
      #pragma unroll
      for (int r = 0; r < 4; ++r) ssum += fmaxf(acc[r] + bias, 0.f);
    }
    ssum += __shfl_xor(ssum, 16, 64);
    ssum += __shfl_xor(ssum, 32, 64);
    if (lg == 0) atomicAdd(&S[((size_t)part*16 + b)*1024 + col], ssum);
  }
}

// ---------------- combine partials: Macc[pb][u] += sum_{f in quarter} S[f]*w2[f][u] ----------------
__global__ void k_combp(const float* __restrict__ S, const float* __restrict__ w2,
                        float* __restrict__ Macc){
  int bid = blockIdx.x; int u = threadIdx.x;
  int pb = bid >> 2, fq = bid & 3;
  const float* Sp = S + (size_t)pb*1024;
  float acc = 0.f;
  for (int f = fq*256; f < fq*256 + 256; ++f) acc += Sp[f] * w2[(size_t)f*128 + u];
  atomicAdd(&Macc[pb*128 + u], acc);
}

// ---------------- Q/R heads (f32) + sum|Q|^2 (folds M = (Mx+Macc)/384 + b2) ----------------
__global__ __launch_bounds__(256) void k_qr(const float* __restrict__ Mx,
    const float* __restrict__ Macc, const float* __restrict__ b2,
    const float* __restrict__ qr_w, const float* __restrict__ qr_b,
    const float* __restrict__ qi_w, const float* __restrict__ qi_b,
    const float* __restrict__ rr_w, const float* __restrict__ rr_b,
    const float* __restrict__ ri_w, const float* __restrict__ ri_b,
    float* __restrict__ out, float* __restrict__ ssq){
  __shared__ float smr[128], smi[128];
  int bid = blockIdx.x; int tid = threadIdx.x;
  int b = bid >> 4; int o = (bid & 15)*256 + tid;
  if (tid < 128){
    smr[tid] = (Mx[b*128 + tid]        + Macc[b*128 + tid]       ) * (1.f/384.f) + b2[tid];
    smi[tid] = (Mx[(16 + b)*128 + tid] + Macc[(16 + b)*128 + tid]) * (1.f/384.f) + b2[tid];
  }
  __syncthreads();
  float aq=0, bq=0, cq=0, dq=0, ar=0, br2=0, cr=0, dr=0;
  for (int u = 0; u < 128; ++u){
    float mr = smr[u], mi = smi[u];
    float wqr = qr_w[(size_t)u*4096 + o], wqi = qi_w[(size_t)u*4096 + o];
    float wrr = rr_w[(size_t)u*4096 + o], wri = ri_w[(size_t)u*4096 + o];
    aq += mr*wqr;  bq += mi*wqi;  cq += mi*wqr;  dq += mr*wqi;
    ar += mr*wrr;  br2 += mi*wri; cr += mi*wrr;  dr += mr*wri;
  }
  float Qr = (aq + qr_b[o]) - (bq + qi_b[o]);
  float Qi = (cq + qr_b[o]) + (dq + qi_b[o]);
  float Rr = (ar + rr_b[o]) - (br2 + ri_b[o]);
  float Ri = (cr + rr_b[o]) + (dr + ri_b[o]);
  out[(size_t)b*4096 + o] = Qr;
  out[65536 + (size_t)b*4096 + o] = Qi;
  out[131072 + (size_t)b*4096 + o] = Rr;
  out[196608 + (size_t)b*4096 + o] = Ri;
  float ss = Qr*Qr + Qi*Qi;
  for (int off = 32; off; off >>= 1) ss += __shfl_down(ss, off, 64);
  if ((tid & 63) == 0) atomicAdd(&ssq[b], ss);
}

// ---------------- scale Q by sqrt(N)/nrm ----------------
__global__ void k_scale(float* __restrict__ out, const float* __restrict__ ssq){
  int i = blockIdx.x*256 + threadIdx.x;   // covers Qr and Qi regions: 131072
  int b = (i >> 12) & 15;
  float s = 8.f / sqrtf(ssq[b]);
  out[i] *= s;
}

extern "C" void kernel_launch(void* const* d_in, const int* in_sizes, int n_in,
                              void* d_out, int out_size, void* d_ws, size_t ws_size,
                              hipStream_t stream){
  const float* h_real = (const float*)d_in[0];
  const float* h_imag = (const float*)d_in[1];
  const float* conv_wr = (const float*)d_in[2];
  const float* conv_wi = (const float*)d_in[3];
  const float* bn_gr = (const float*)d_in[4];
  const float* bn_gi = (const float*)d_in[5];
  const float* bn_vr = (const float*)d_in[6];
  const float* bn_vi = (const float*)d_in[7];
  const float* bn_br = (const float*)d_in[8];
  const float* bn_bi = (const float*)d_in[9];
  const float* bn_mr = (const float*)d_in[10];
  const float* bn_mi = (const float*)d_in[11];
  const float* g0_kr = (const float*)d_in[12];
  const float* g0_rkr = (const float*)d_in[13];
  const float* g0_br = (const float*)d_in[14];
  const float* g0_ki = (const float*)d_in[15];
  const float* g0_rki = (const float*)d_in[16];
  const float* g0_bi = (const float*)d_in[17];
  const float* gs_kr = (const float*)d_in[18];
  const float* gs_rkr = (const float*)d_in[19];
  const float* gs_br = (const float*)d_in[20];
  const float* gs_ki = (const float*)d_in[21];
  const float* gs_rki = (const float*)d_in[22];
  const float* gs_bi = (const float*)d_in[23];
  const float* ff1_w = (const float*)d_in[24];
  const float* ff1_b = (const float*)d_in[25];
  const float* ff2_w = (const float*)d_in[26];
  const float* ff2_b = (const float*)d_in[27];
  const float* qr_w = (const float*)d_in[28];
  const float* qr_b = (const float*)d_in[29];
  const float* qi_w = (const float*)d_in[30];
  const float* qi_b = (const float*)d_in[31];
  const float* rr_w = (const float*)d_in[32];
  const float* rr_b = (const float*)d_in[33];
  const float* ri_w = (const float*)d_in[34];
  const float* ri_b = (const float*)d_in[35];

  char* ws = (char*)d_ws; size_t off = 0;
  auto carve = [&](size_t bytes)->char*{ char* p = ws + off; off += (bytes + 255) & ~(size_t)255; return p; };
  u16* X0   = (u16*)carve((size_t)2*16*384*64*2);          // 1.5 MB
  u16* HC   = (u16*)carve((size_t)64*RING*CHSZ*2);         // 16.8 MB chunk ring
  u16* HS15 = (u16*)carve((size_t)4*16*384*128*2);         // 6.3 MB (layer-15 full-seq streams)
  u16* KT   = (u16*)carve((size_t)16*2*384*128*2);         // 3.1 MB
  u16* RKT  = (u16*)carve((size_t)16*2*384*128*2);         // 3.1 MB
  u16* WtR  = (u16*)carve(131072*2);
  u16* WtI  = (u16*)carve(131072*2);
  u16* W1t  = (u16*)carve(131072*2);
  u32* Flg  = (u32*)carve(4608*4);                         // prod/cons/conv flags (128B padded)
  float* S  = (float*)carve(32768*4);
  float* Mx = (float*)carve(4096*4);
  float* Macc = (float*)carve(4096*4);
  float* ssq = (float*)carve(256);

  k_pro<<<1971, 256, 0, stream>>>(S, ssq, Flg, Mx, Macc,
                                  conv_wr, conv_wi, ff1_w, WtR, WtI, W1t,
                                  g0_kr, g0_ki, gs_kr, gs_ki,
                                  g0_rkr, g0_rki, gs_rkr, gs_rki, KT, RKT);
  k_scanp<<<256, 512, 0, stream>>>(X0, KT, RKT, g0_br, g0_bi, gs_br, gs_bi,
                                   HC, HS15, Flg,
                                   h_real, h_imag, WtR, WtI,
                                   bn_gr, bn_gi, bn_vr, bn_vi, bn_br, bn_bi, bn_mr, bn_mi);
  k_ffs<<<768, 256, 0, stream>>>(HS15, W1t, ff1_b, S, Mx);
  k_combp<<<128, 128, 0, stream>>>(S, ff2_w, Macc);
  k_qr<<<256, 256, 0, stream>>>(Mx, Macc, ff2_b, qr_w, qr_b, qi_w, qi_b,
                                rr_w, rr_b, ri_w, ri_b, (float*)d_out, ssq);
  k_scale<<<512, 256, 0, stream>>>((float*)d_out, ssq);
}